// Round 16
// baseline (141.282 us; speedup 1.0000x reference)
//
#include <hip/hip_runtime.h>
#include <stdint.h>

#define DEV static __device__ __forceinline__

typedef __attribute__((ext_vector_type(8))) short s16x8;   // 8 bf16 in 4 VGPRs
typedef __attribute__((ext_vector_type(4))) float f32x4;   // MFMA acc

// ---------- problem constants ----------
constexpr int Bdim = 2, Sdim = 2048, Ddim = 1024, Hdim = 16, DH = 64;
constexpr int Mrows = Bdim * Sdim;      // 4096
constexpr int NB = 32;                  // S / 64
constexpr int SEL_STRIDE = 18;          // [count, up to 17 block ids]

// Q prescale folded into QKV epilogue: 1/sqrt(64) * log2(e)
#define QSCALE 0.18033688011112042f
#define MFIX   8.0f                     // fixed softmax max (log2 domain, >=5 sigma margin)

// ---------- workspace layout (bytes) ----------
constexpr size_t OFF_XB    = 0;                                        // x bf16 [4096][1024]
constexpr size_t OFF_WTQKV = OFF_XB    + (size_t)Mrows*Ddim*2;         // Wqkv^T bf16 [3072][1024]
constexpr size_t OFF_WOT   = OFF_WTQKV + (size_t)3072*1024*2;          // Wo^T bf16 [1024][1024]
constexpr size_t OFF_QKV   = OFF_WOT   + (size_t)1024*1024*2;          // qkv bf16 [4096][3072]
constexpr size_t OFF_CTX   = OFF_QKV   + (size_t)Mrows*3072*2;         // ctx bf16 [4096][1024]
constexpr size_t OFF_XM    = OFF_CTX   + (size_t)Mrows*Ddim*2;         // xm f32 [64][1024]
constexpr size_t OFF_QM    = OFF_XM    + (size_t)64*1024*4;            // qm f32 [64][1024]
constexpr size_t OFF_KM    = OFF_QM    + (size_t)64*1024*4;            // km f32 [64][1024]
constexpr size_t OFF_BIASQ = OFF_KM    + (size_t)64*1024*4;            // f32 [3072]
constexpr size_t OFF_SEL   = OFF_BIASQ + (size_t)3072*4;               // int [1024][18]
constexpr size_t OFF_PART  = OFF_SEL   + (size_t)1024*SEL_STRIDE*4;    // f32 [2][8][64][1024]

DEV float bf2f(unsigned short u){ union{unsigned int i; float f;} x; x.i = ((unsigned int)u)<<16; return x.f; }
DEV unsigned short f2bf(float f){ union{float f; unsigned int i;} x; x.f=f;
  unsigned int r = x.i + 0x7fffu + ((x.i>>16)&1u); return (unsigned short)(r>>16); }

// global -> LDS async 16B (per-wave: lane l writes ldsbase + l*16)
DEV void gload16(const unsigned short* g, unsigned short* l){
  __builtin_amdgcn_global_load_lds(
      (__attribute__((address_space(1))) void*)(void*)g,
      (__attribute__((address_space(3))) void*)l, 16, 0, 0);
}

DEV unsigned int cvtpk(float a, float b){
  unsigned int r;
  asm("v_cvt_pk_bf16_f32 %0, %1, %2" : "=v"(r) : "v"(a), "v"(b));
  return r;
}

DEV float exp2fast(float x){           // D = 2^x (v_exp_f32 is natively base-2)
  float r;
  asm("v_exp_f32 %0, %1" : "=v"(r) : "v"(x));
  return r;
}

// =============================================================
// prep: fused {ln (blocks 0..4095), xm (4096..4159),
//              wtrans4+biascat (4160..8255)} — all input-only.
// =============================================================
__global__ __launch_bounds__(256) void prep_kernel(const float* __restrict__ inp,
                                                   const float* __restrict__ gam,
                                                   const float* __restrict__ bet,
                                                   const float* __restrict__ Wq,
                                                   const float* __restrict__ Wk,
                                                   const float* __restrict__ Wv,
                                                   const float* __restrict__ Wo,
                                                   const float* __restrict__ bq,
                                                   const float* __restrict__ bk,
                                                   const float* __restrict__ bv,
                                                   unsigned short* __restrict__ xb,
                                                   float* __restrict__ xm,
                                                   unsigned short* __restrict__ wtqkv,
                                                   unsigned short* __restrict__ wot,
                                                   float* __restrict__ bqkv){
  __shared__ float sh[4][1024];          // 16KB union for all three roles
  const int bid = blockIdx.x;
  const int t = threadIdx.x;

  if (bid < 4096){
    // ---------------- ln: one row ----------------
    const int row = bid;
    float* red = &sh[0][0];
    const float4 v = ((const float4*)(inp + (size_t)row*Ddim))[t];
    float s  = v.x + v.y + v.z + v.w;
    float s2 = v.x*v.x + v.y*v.y + v.z*v.z + v.w*v.w;
#pragma unroll
    for (int mk=32; mk>=1; mk>>=1){ s += __shfl_xor(s, mk); s2 += __shfl_xor(s2, mk); }
    if ((t&63)==0){ red[t>>6] = s; red[4+(t>>6)] = s2; }
    __syncthreads();
    s  = red[0]+red[1]+red[2]+red[3];
    s2 = red[4]+red[5]+red[6]+red[7];
    const float mu  = s * (1.f/Ddim);
    const float var = s2 * (1.f/Ddim) - mu*mu;
    const float rs  = rsqrtf(var + 1e-5f);
    const float4 gv = ((const float4*)gam)[t];
    const float4 bv2 = ((const float4*)bet)[t];
    float o0 = (v.x-mu)*rs*gv.x + bv2.x;
    float o1 = (v.y-mu)*rs*gv.y + bv2.y;
    float o2 = (v.z-mu)*rs*gv.z + bv2.z;
    float o3 = (v.w-mu)*rs*gv.w + bv2.w;
    uint2 u;
    u.x = (unsigned int)f2bf(o0) | ((unsigned int)f2bf(o1)<<16);
    u.y = (unsigned int)f2bf(o2) | ((unsigned int)f2bf(o3)<<16);
    ((uint2*)(xb + (size_t)row*Ddim))[t] = u;
  } else if (bid < 4160){
    // ---------------- xm: one 64-row block ----------------
    const int blk = bid - 4096;
    const int w = t>>6, lane = t&63;
    float4 gv[4], bvv[4];
#pragma unroll
    for (int p=0;p<4;++p){ gv[p] = ((const float4*)gam)[lane + 64*p];
                           bvv[p] = ((const float4*)bet)[lane + 64*p]; }
    float ax[4][4];
#pragma unroll
    for (int p=0;p<4;++p)
#pragma unroll
      for (int c=0;c<4;++c) ax[p][c]=0.f;
    for (int rr=0; rr<16; ++rr){
      const int row = blk*64 + w*16 + rr;
      const float4* rp = (const float4*)(inp + (size_t)row*Ddim);
      float4 v[4]; float s=0.f, s2=0.f;
#pragma unroll
      for (int p=0;p<4;++p){
        v[p] = rp[lane + 64*p];
        s  += v[p].x+v[p].y+v[p].z+v[p].w;
        s2 += v[p].x*v[p].x+v[p].y*v[p].y+v[p].z*v[p].z+v[p].w*v[p].w;
      }
#pragma unroll
      for (int mk=32; mk>=1; mk>>=1){ s += __shfl_xor(s,mk); s2 += __shfl_xor(s2,mk); }
      const float mu = s*(1.f/Ddim);
      const float var = s2*(1.f/Ddim) - mu*mu;
      const float rs = rsqrtf(var + 1e-5f);
#pragma unroll
      for (int p=0;p<4;++p){
        ax[p][0] += (v[p].x-mu)*rs*gv[p].x + bvv[p].x;
        ax[p][1] += (v[p].y-mu)*rs*gv[p].y + bvv[p].y;
        ax[p][2] += (v[p].z-mu)*rs*gv[p].z + bvv[p].z;
        ax[p][3] += (v[p].w-mu)*rs*gv[p].w + bvv[p].w;
      }
    }
#pragma unroll
    for (int p=0;p<4;++p){
      float4 o; o.x=ax[p][0]; o.y=ax[p][1]; o.z=ax[p][2]; o.w=ax[p][3];
      ((float4*)&sh[w][0])[lane + 64*p] = o;
    }
    __syncthreads();
    float4 r0 = ((float4*)&sh[0][0])[t];
    float4 r1 = ((float4*)&sh[1][0])[t];
    float4 r2 = ((float4*)&sh[2][0])[t];
    float4 r3 = ((float4*)&sh[3][0])[t];
    float4 o;
    o.x = (r0.x+r1.x+r2.x+r3.x)*(1.f/64);
    o.y = (r0.y+r1.y+r2.y+r3.y)*(1.f/64);
    o.z = (r0.z+r1.z+r2.z+r3.z)*(1.f/64);
    o.w = (r0.w+r1.w+r2.w+r3.w)*(1.f/64);
    ((float4*)(xm + (size_t)blk*Ddim))[t] = o;
  } else {
    // ---------------- wtrans: one 32x32 tile ----------------
    const int wt = bid - 4160;
    const int z = wt >> 10, rem = wt & 1023;
    const int bx = rem & 31, by = rem >> 5;
    const float* W = (z==0)?Wq:(z==1)?Wk:(z==2)?Wv:Wo;
    unsigned short* Wt = (z<3) ? (wtqkv + (size_t)z*1024*1024) : wot;
    const int n0 = bx*32, k0 = by*32;
    const int r = t>>5, c = t&31;
    float (*tile)[33] = (float(*)[33])&sh[0][0];
    if (z<3 && bx==0 && by==0){
      const float* bb = (z==0)?bq:(z==1)?bk:bv;
#pragma unroll
      for (int i=0;i<4;++i) bqkv[z*1024 + t + 256*i] = bb[t + 256*i];
    }
#pragma unroll
    for (int i=0;i<4;++i) tile[r+8*i][c] = W[(size_t)(k0 + r + 8*i)*1024 + n0 + c];
    __syncthreads();
    const int nr = t >> 3, kq = (t & 7) * 4;
    unsigned int w0 = (unsigned int)f2bf(tile[kq  ][nr]) | ((unsigned int)f2bf(tile[kq+1][nr])<<16);
    unsigned int w1 = (unsigned int)f2bf(tile[kq+2][nr]) | ((unsigned int)f2bf(tile[kq+3][nr])<<16);
    uint2 st; st.x = w0; st.y = w1;
    *(uint2*)&Wt[(size_t)(n0 + nr)*1024 + k0 + kq] = st;
  }
}

// =============================================================
// qm/km partials: k-split exact fp32 GEMM (round-5 proven version)
// =============================================================
__global__ __launch_bounds__(256) void qmkm_part(const float* __restrict__ xm,
    const float* __restrict__ Wq, const float* __restrict__ Wk,
    float* __restrict__ part){
  const int c  = blockIdx.x*256 + threadIdx.x;
  const int rg = blockIdx.y >> 3, ks = blockIdx.y & 7;
  const int z  = blockIdx.z;
  const float* W = z ? Wk : Wq;
  const int r0 = rg*16, k0 = ks*128;
  float acc[16];
#pragma unroll
  for (int r=0;r<16;++r) acc[r]=0.f;
  for (int k=0;k<128;k+=4){
    const float wv0 = W[(size_t)(k0+k  )*1024 + c];
    const float wv1 = W[(size_t)(k0+k+1)*1024 + c];
    const float wv2 = W[(size_t)(k0+k+2)*1024 + c];
    const float wv3 = W[(size_t)(k0+k+3)*1024 + c];
#pragma unroll
    for (int r=0;r<16;++r){
      const float4 xv = *(const float4*)&xm[(size_t)(r0+r)*1024 + k0 + k];
      acc[r] = fmaf(xv.w, wv3, fmaf(xv.z, wv2, fmaf(xv.y, wv1, fmaf(xv.x, wv0, acc[r]))));
    }
  }
  float* dst = part + (((size_t)z*8 + ks)*64 + r0)*1024 + c;
#pragma unroll
  for (int r=0;r<16;++r) dst[(size_t)r*1024] = acc[r];
}

__global__ __launch_bounds__(256) void qmkm_reduce(const float* __restrict__ part,
    const float* __restrict__ bq, const float* __restrict__ bk,
    float* __restrict__ qm, float* __restrict__ km){
  const int idx = blockIdx.x*256 + threadIdx.x;
  const int z = blockIdx.y;
  const int c = idx & 1023, r = idx >> 10;
  const float* p = part + ((size_t)z*8*64*1024) + (size_t)r*1024 + c;
  float s = 0.f;
#pragma unroll
  for (int ks=0; ks<8; ++ks) s += p[(size_t)ks*64*1024];
  s += z ? bk[c] : bq[c];
  (z ? km : qm)[(size_t)r*1024 + c] = s;
}

// =============================================================
// block similarity + top-16 selection (matches jax.lax.top_k ties)
// =============================================================
__global__ __launch_bounds__(256) void topk_kernel(const float* __restrict__ qm,
                                                   const float* __restrict__ km,
                                                   int* __restrict__ sel){
  const int bhq = blockIdx.x;
  const int qb = bhq & 31, h = (bhq>>5) & 15, b = bhq >> 9;
  const int t = threadIdx.x;
  __shared__ float sim[32];
  __shared__ int keep[32];
  const int kb = t>>3, l8 = t&7;
  float acc = 0.f;
  if (kb <= qb){
    const float* qv = qm + (size_t)(b*32 + qb)*1024 + h*64;
    const float* kv = km + (size_t)(b*32 + kb)*1024 + h*64;
#pragma unroll
    for (int d=0; d<8; ++d) acc += qv[l8*8+d] * kv[l8*8+d];
  }
  acc += __shfl_xor(acc,1); acc += __shfl_xor(acc,2); acc += __shfl_xor(acc,4);
  if (l8==0) sim[kb] = (kb<=qb) ? acc : -1e30f;
  __syncthreads();
  if (t < 32){
    int k2 = t; int ok = 0;
    if (k2 <= qb){
      float sv = sim[k2]; int rank = 0;
      for (int j=0;j<=qb;++j){
        float sj = sim[j];
        rank += (sj > sv) || (sj == sv && j < k2);
      }
      ok = (rank < 16) || (k2 == qb);
    }
    keep[t] = ok;
  }
  __syncthreads();
  if (t == 0){
    int* dstp = sel + (size_t)bhq * SEL_STRIDE;
    int c = 0;
    for (int j=0;j<32;++j) if (keep[j]) dstp[1+c++] = j;
    dstp[0] = c;
  }
}

// =============================================================
// bf16 MFMA GEMM (QKV): 128x128, BK=32 TRIPLE-BUFFERED depth-2
// pipeline (vmcnt(8) steady state). 2-D XCD partition. SCALEQ folds
// attn's log2-domain Q prescale into the epilogue. (proven r12)
// =============================================================
#define G_STAGE(bsel, kofs) do { \
  gload16(A0 + (kofs), ldsA + (bsel)*4096 + (wid*2+0)*512); \
  gload16(A1 + (kofs), ldsA + (bsel)*4096 + (wid*2+1)*512); \
  gload16(B0 + (kofs), ldsB + (bsel)*4096 + (wid*2+0)*512); \
  gload16(B1 + (kofs), ldsB + (bsel)*4096 + (wid*2+1)*512); \
} while(0)

#define G_COMPUTE(bsel) do { \
  s16x8 af[4], bfr[4]; \
  _Pragma("unroll") \
  for (int mi=0;mi<4;++mi){ \
    int row = wr*64 + mi*16 + rl; \
    af[mi] = *(const s16x8*)((char*)ldsA + (bsel)*8192 + row*64 + ((g ^ ((row>>1)&3))<<4)); \
  } \
  _Pragma("unroll") \
  for (int ni=0;ni<4;++ni){ \
    int row = wc*64 + ni*16 + rl; \
    bfr[ni] = *(const s16x8*)((char*)ldsB + (bsel)*8192 + row*64 + ((g ^ ((row>>1)&3))<<4)); \
  } \
  _Pragma("unroll") \
  for (int mi=0;mi<4;++mi) \
    _Pragma("unroll") \
    for (int ni=0;ni<4;++ni) \
      acc[mi][ni] = __builtin_amdgcn_mfma_f32_16x16x32_bf16(af[mi], bfr[ni], acc[mi][ni], 0,0,0); \
} while(0)

template<int OUT_BF16, int SCALEQ>
__global__ __launch_bounds__(256) void gemm_bt(const unsigned short* __restrict__ A,
                                               const unsigned short* __restrict__ Bt,
                                               const float* __restrict__ bias,
                                               void* __restrict__ C, int N){
  constexpr int K = 1024;
  constexpr int NT = K/32;                          // 32 K-tiles
  __shared__ unsigned short ldsA[3*128*32];
  __shared__ unsigned short ldsB[3*128*32];
  const int t = threadIdx.x, lane = t & 63, wid = t >> 6;
  const int wr = wid >> 1, wc = wid & 1;
  const int rl = lane & 15, g = lane >> 4;

  const int nbx = gridDim.x, nby = gridDim.y;
  const int id  = blockIdx.y * nbx + blockIdx.x;
  const int xcd = id & 7, j = id >> 3;
  const int MBP = nby >> 2, NBP = nbx >> 1;
  const int mg = xcd >> 1, ng = xcd & 1;
  const int m0 = (mg*MBP + (j % MBP)) * 128;
  const int n0 = (ng*NBP + (j / MBP)) * 128;

  const f32x4 ZERO4 = {0.f,0.f,0.f,0.f};
  f32x4 acc[4][4];
#pragma unroll
  for (int i=0;i<4;++i)
#pragma unroll
    for (int j2=0;j2<4;++j2) acc[i][j2] = ZERO4;

  const int slot0 = wid*128 + lane, slot1 = slot0 + 64;
  const int sr0 = slot0>>2, sc0 = slot0&3;
  const int sr1 = slot1>>2, sc1 = slot1&3;
  const unsigned short* A0 = A  + (size_t)(m0 + sr0)*K + (sc0 ^ ((sr0>>1)&3))*8;
  const unsigned short* A1 = A  + (size_t)(m0 + sr1)*K + (sc1 ^ ((sr1>>1)&3))*8;
  const unsigned short* B0 = Bt + (size_t)(n0 + sr0)*K + (sc0 ^ ((sr0>>1)&3))*8;
  const unsigned short* B1 = Bt + (size_t)(n0 + sr1)*K + (sc1 ^ ((sr1>>1)&3))*8;

  G_STAGE(0, 0);
  G_STAGE(1, 32);

  for (int ti=0; ti<NT; ++ti){
    const int cur = ti % 3;
    if (ti+2 < NT){
      G_STAGE((ti+2)%3, (ti+2)*32);
      asm volatile("s_waitcnt vmcnt(8)" ::: "memory");
    } else if (ti+1 < NT){
      asm volatile("s_waitcnt vmcnt(4)" ::: "memory");
    } else {
      asm volatile("s_waitcnt vmcnt(0)" ::: "memory");
    }
    __builtin_amdgcn_s_barrier();
    __builtin_amdgcn_sched_barrier(0);
    G_COMPUTE(cur);
    __builtin_amdgcn_sched_barrier(0);
    __builtin_amdgcn_s_barrier();
  }

  const int r4 = g*4;
#pragma unroll
  for (int mi=0;mi<4;++mi){
#pragma unroll
    for (int ni=0;ni<4;++ni){
      int col = n0 + wc*64 + ni*16 + rl;
      float bb = bias[col];
      float sc = (SCALEQ && col < 1024) ? QSCALE : 1.0f;
#pragma unroll
      for (int e=0;e<4;++e){
        int row = m0 + wr*64 + mi*16 + r4 + e;
        float v = (acc[mi][ni][e] + bb) * sc;
        if (OUT_BF16) ((unsigned short*)C)[(size_t)row*N + col] = f2bf(v);
        else          ((float*)C)[(size_t)row*N + col] = v;
      }
    }
  }
}

// =============================================================
// O-proj GEMM: 128x64 tile, BK=32 triple-buffer counted-vmcnt
// pipeline (vmcnt(6) steady). (proven r15)
// =============================================================
#define G64_STAGE(bsel, kofs) do { \
  gload16(A0 + (kofs), ldsA + (bsel)*4096 + (wid*2+0)*512); \
  gload16(A1 + (kofs), ldsA + (bsel)*4096 + (wid*2+1)*512); \
  gload16(B0 + (kofs), ldsB + (bsel)*2048 + wid*512); \
} while(0)

#define G64_COMPUTE(bsel) do { \
  s16x8 af[4], bfr[2]; \
  _Pragma("unroll") \
  for (int mi=0;mi<4;++mi){ \
    int row = wr*64 + mi*16 + rl; \
    af[mi] = *(const s16x8*)((char*)ldsA + (bsel)*8192 + row*64 + ((g ^ ((row>>1)&3))<<4)); \
  } \
  _Pragma("unroll") \
  for (int ni=0;ni<2;++ni){ \
    int row = wc*32 + ni*16 + rl; \
    bfr[ni] = *(const s16x8*)((char*)ldsB + (bsel)*4096 + row*64 + ((g ^ ((row>>1)&3))<<4)); \
  } \
  _Pragma("unroll") \
  for (int mi=0;mi<4;++mi) \
    _Pragma("unroll") \
    for (int ni=0;ni<2;++ni) \
      acc[mi][ni] = __builtin_amdgcn_mfma_f32_16x16x32_bf16(af[mi], bfr[ni], acc[mi][ni], 0,0,0); \
} while(0)

__global__ __launch_bounds__(256) void gemm_bt64(const unsigned short* __restrict__ A,
                                                 const unsigned short* __restrict__ Bt,
                                                 const float* __restrict__ bias,
                                                 float* __restrict__ C, int N){
  constexpr int K = 1024;
  constexpr int NT = K/32;
  __shared__ unsigned short ldsA[3*128*32];
  __shared__ unsigned short ldsB[3*64*32];
  const int t = threadIdx.x, lane = t & 63, wid = t >> 6;
  const int wr = wid >> 1, wc = wid & 1;
  const int rl = lane & 15, g = lane >> 4;

  const int id  = blockIdx.y * gridDim.x + blockIdx.x;
  const int xcd = id & 7, j = id >> 3;            // j 0..63
  const int mg = xcd >> 1, ng = xcd & 1;
  const int m0 = (mg*8 + (j & 7)) * 128;          // 32 m-blocks
  const int n0 = (ng*8 + (j >> 3)) * 64;          // 16 n-blocks

  const f32x4 ZERO4 = {0.f,0.f,0.f,0.f};
  f32x4 acc[4][2];
#pragma unroll
  for (int i=0;i<4;++i)
#pragma unroll
    for (int j2=0;j2<2;++j2) acc[i][j2] = ZERO4;

  const int slot0 = wid*128 + lane, slot1 = slot0 + 64;
  const int sr0 = slot0>>2, sc0 = slot0&3;
  const int sr1 = slot1>>2, sc1 = slot1&3;
  const unsigned short* A0 = A + (size_t)(m0 + sr0)*K + (sc0 ^ ((sr0>>1)&3))*8;
  const unsigned short* A1 = A + (size_t)(m0 + sr1)*K + (sc1 ^ ((sr1>>1)&3))*8;
  const int slotB = wid*64 + lane;
  const int srB = slotB>>2, scB = slotB&3;
  const unsigned short* B0 = Bt + (size_t)(n0 + srB)*K + (scB ^ ((srB>>1)&3))*8;

  G64_STAGE(0, 0);
  G64_STAGE(1, 32);

  for (int ti=0; ti<NT; ++ti){
    const int cur = ti % 3;
    if (ti+2 < NT){
      G64_STAGE((ti+2)%3, (ti+2)*32);
      asm volatile("s_waitcnt vmcnt(6)" ::: "memory");
    } else if (ti+1 < NT){
      asm volatile("s_waitcnt vmcnt(3)" ::: "memory");
    } else {
      asm volatile("s_waitcnt vmcnt(0)" ::: "memory");
    }
    __builtin_amdgcn_s_barrier();
    __builtin_amdgcn_sched_barrier(0);
    G64_COMPUTE(cur);
    __builtin_amdgcn_sched_barrier(0);
    __builtin_amdgcn_s_barrier();
  }

  const int r4 = g*4;
#pragma unroll
  for (int mi=0;mi<4;++mi){
#pragma unroll
    for (int ni=0;ni<2;++ni){
      int col = n0 + wc*32 + ni*16 + rl;
      float bb = bias[col];
#pragma unroll
      for (int e=0;e<4;++e){
        int row = m0 + wr*64 + mi*16 + r4 + e;
        C[(size_t)row*N + col] = acc[mi][ni][e] + bb;
      }
    }
  }
}

// =============================================================
// Sparse flash attention v8: same per-iter body as proven v6, but
// UNPAIRED decomposition — grid 1024, one qb per block (4 blocks/CU,
// LDS cap 5), heavy blocks (qb>=16, ns=17) dispatched first.
// Zero added work vs v6 (13,056 block-iters either way).
// =============================================================
__global__ __launch_bounds__(256) void attn_kernel(const unsigned short* __restrict__ qkv,
                                                   const int* __restrict__ sel,
                                                   unsigned short* __restrict__ ctx){
  const int id = blockIdx.x;                 // 0..1023
  const int xcd = id & 7, jj = id >> 3;      // jj 0..127
  const int bh = xcd + 8*(jj >> 5);          // XCD-pinned (b,h)
  const int qb = 31 - (jj & 31);             // heavy-first dispatch
  const int h = bh & 15, b = bh >> 4;

  const int t = threadIdx.x, wid = t >> 6, lane = t & 63;
  const int rl = lane & 15, g = lane >> 4;
  const int q_local = wid*16 + rl;

  __shared__ unsigned short K_s[2][4096];    // [j 64][128B], chunk^(j&7) swizzle
  __shared__ unsigned short V_s[2][4096];    // V^T [d 64][128B], chunk^((d&7)^(d>>3))

  const int jst = t >> 2, cq = t & 3;        // K: row jst, chunks 2cq, 2cq+1
  const int r2 = t >> 3, dq = t & 7;         // V: rows 2r2,2r2+1, d-base dq*8
  const unsigned short* kbase = qkv + (size_t)(b*Sdim + jst)*3072 + 1024 + h*DH + cq*16;
  const unsigned short* vbase = qkv + (size_t)(b*Sdim + 2*r2)*3072 + 2048 + h*DH + dq*8;
  const int kwb0 = jst*128 + (((cq*2  ) ^ (jst&7))<<4);
  const int kwb1 = jst*128 + (((cq*2+1) ^ (jst&7))<<4);
  const f32x4 ZERO4 = {0.f,0.f,0.f,0.f};

  const int src0 = (rl + 16*((2*g  ) & 3)) << 2;
  const int src1 = (rl + 16*((2*g+1) & 3)) << 2;
  const bool hsel = (g >> 1);

  const int* selrow = sel + (size_t)(((b*Hdim)+h)*NB + qb) * SEL_STRIDE;
  const int ns = selrow[0];

  const int qg0 = b*Sdim + qb*64 + q_local;
  const unsigned short* qbase = qkv + (size_t)qg0*3072 + h*DH;
  s16x8 qa[2];                 // raw loads — prescale done in GEMM epilogue
  qa[0] = *(const s16x8*)(qbase + g*8);
  qa[1] = *(const s16x8*)(qbase + 32 + g*8);

  f32x4 o[4];                  // O^T: o[f][e] = O[q=q_local][d = f*16 + g*4 + e]
  float l_p = 0.f;             // per-lane partial denominator
#pragma unroll
  for (int f=0; f<4; ++f) o[f] = ZERO4;

  int kb = selrow[1];
  s16x8 kr0, kr1, vr0, vr1;
  {
    const size_t off = (size_t)kb*64*3072;
    kr0 = *(const s16x8*)(kbase + off);
    kr1 = *(const s16x8*)(kbase + off + 8);
    vr0 = *(const s16x8*)(vbase + off);
    vr1 = *(const s16x8*)(vbase + off + 3072);
  }

  for (int it=0; it<ns; ++it){
    const int buf = it & 1;
    unsigned short* Kw = &K_s[buf][0];
    unsigned short* Vw = &V_s[buf][0];
    *(s16x8*)((char*)Kw + kwb0) = kr0;
    *(s16x8*)((char*)Kw + kwb1) = kr1;
#pragma unroll
    for (int e=0;e<8;++e){
      const int d1 = dq*8 + e;
      const int sw = (d1&7) ^ (d1>>3);
      const unsigned int pr = (unsigned int)(unsigned short)vr0[e]
                            | ((unsigned int)(unsigned short)vr1[e] << 16);
      *(unsigned int*)((char*)Vw + d1*128 + ((4*r2) ^ (sw<<4))) = pr;
    }
    const int kbcur = kb;
    if (it+1 < ns){
      kb = selrow[2+it];
      const size_t off = (size_t)kb*64*3072;
      kr0 = *(const s16x8*)(kbase + off);
      kr1 = *(const s16x8*)(kbase + off + 8);
      vr0 = *(const s16x8*)(vbase + off);
      vr1 = *(const s16x8*)(vbase + off + 3072);
    }
    __syncthreads();

    // ---- S^T = K Q'^T  (log2 domain via Q prescale) ----
    f32x4 sfT[4];
#pragma unroll
    for (int f=0;f<4;++f) sfT[f] = ZERO4;
    __builtin_amdgcn_s_setprio(1);
#pragma unroll
    for (int kk=0;kk<2;++kk){
#pragma unroll
      for (int f=0;f<4;++f){
        const int jr = f*16 + rl;
        s16x8 kf = *(const s16x8*)((char*)Kw + jr*128 + (((kk*4+g) ^ (jr&7))<<4));
        sfT[f] = __builtin_amdgcn_mfma_f32_16x16x32_bf16(kf, qa[kk], sfT[f], 0,0,0);
      }
    }
    __builtin_amdgcn_s_setprio(0);
    if (kbcur == qb){
#pragma unroll
      for (int f=0;f<4;++f)
#pragma unroll
        for (int e=0;e<4;++e){
          const int j2 = f*16 + g*4 + e;
          if (j2 > q_local) sfT[f][e] = -1e9f;
        }
    }
    // ---- fixed-max softmax weights: p = 2^(S - MFIX) ----
    {
      float rs = 0.f;
#pragma unroll
      for (int f=0;f<4;++f)
#pragma unroll
        for (int e=0;e<4;++e){
          const float p = exp2fast(sfT[f][e] - MFIX);
          sfT[f][e] = p; rs += p;
        }
      l_p += rs;
    }

    unsigned int plo[4], phi[4];
#pragma unroll
    for (int f=0;f<4;++f){
      plo[f] = cvtpk(sfT[f][0], sfT[f][1]);
      phi[f] = cvtpk(sfT[f][2], sfT[f][3]);
    }

#pragma unroll
    for (int kk=0;kk<2;++kk){
      const int f0 = 2*kk, f1 = 2*kk+1;
      unsigned int a0, b0, w0, w1, w2, w3;
      a0 = __builtin_amdgcn_ds_bpermute(src0, plo[f0]);
      b0 = __builtin_amdgcn_ds_bpermute(src0, plo[f1]);
      w0 = hsel ? b0 : a0;
      a0 = __builtin_amdgcn_ds_bpermute(src0, phi[f0]);
      b0 = __builtin_amdgcn_ds_bpermute(src0, phi[f1]);
      w1 = hsel ? b0 : a0;
      a0 = __builtin_amdgcn_ds_bpermute(src1, plo[f0]);
      b0 = __builtin_amdgcn_ds_bpermute(src1, plo[f1]);
      w2 = hsel ? b0 : a0;
      a0 = __builtin_amdgcn_ds_bpermute(src1, phi[f0]);
      b0 = __builtin_amdgcn_ds_bpermute(src1, phi[f1]);
      w3 = hsel ? b0 : a0;
      union { unsigned int u[4]; s16x8 v; } pfc;
      pfc.u[0] = w0; pfc.u[1] = w1; pfc.u[2] = w2; pfc.u[3] = w3;
      const s16x8 pf = pfc.v;
      __builtin_amdgcn_s_setprio(1);
#pragma unroll
      for (int f=0;f<4;++f){
        const int d = f*16 + rl;
        const int sw = (d&7) ^ (d>>3);
        s16x8 vf = *(const s16x8*)((char*)Vw + d*128 + ((64*kk + 16*g) ^ (sw<<4)));
        o[f] = __builtin_amdgcn_mfma_f32_16x16x32_bf16(vf, pf, o[f], 0,0,0);
      }
      __builtin_amdgcn_s_setprio(0);
    }
  }

  {
    float l_r = l_p;
    l_r += __shfl_xor(l_r, 16);
    l_r += __shfl_xor(l_r, 32);
    const float inv = 1.f / l_r;
    unsigned short* crow = ctx + (size_t)qg0*Ddim + h*DH;
#pragma unroll
    for (int f=0;f<4;++f){
      uint2 st;
      st.x = (unsigned int)f2bf(o[f][0]*inv) | ((unsigned int)f2bf(o[f][1]*inv)<<16);
      st.y = (unsigned int)f2bf(o[f][2]*inv) | ((unsigned int)f2bf(o[f][3]*inv)<<16);
      *(uint2*)(crow + f*16 + g*4) = st;
    }
  }
}

// =============================================================
extern "C" void kernel_launch(void* const* d_in, const int* in_sizes, int n_in,
                              void* d_out, int out_size, void* d_ws, size_t ws_size,
                              hipStream_t stream){
  (void)in_sizes; (void)n_in; (void)out_size; (void)ws_size;
  const float* inp  = (const float*)d_in[0];
  const float* ln_g = (const float*)d_in[1];
  const float* ln_b = (const float*)d_in[2];
  const float* Wq   = (const float*)d_in[3];
  const float* bq   = (const float*)d_in[4];
  const float* Wk   = (const float*)d_in[5];
  const float* bk   = (const float*)d_in[6];
  const float* Wv   = (const float*)d_in[7];
  const float* bv   = (const float*)d_in[8];
  const float* Wo   = (const float*)d_in[9];
  const float* bo   = (const float*)d_in[10];

  char* ws = (char*)d_ws;
  unsigned short* xb    = (unsigned short*)(ws + OFF_XB);
  unsigned short* wtqkv = (unsigned short*)(ws + OFF_WTQKV);
  unsigned short* wot   = (unsigned short*)(ws + OFF_WOT);
  unsigned short* qkvb  = (unsigned short*)(ws + OFF_QKV);
  unsigned short* ctx   = (unsigned short*)(ws + OFF_CTX);
  float* xm   = (float*)(ws + OFF_XM);
  float* qm   = (float*)(ws + OFF_QM);
  float* km   = (float*)(ws + OFF_KM);
  float* bqkv = (float*)(ws + OFF_BIASQ);
  int*   sel  = (int*)(ws + OFF_SEL);
  float* part = (float*)(ws + OFF_PART);

  prep_kernel<<<8256, 256, 0, stream>>>(inp, ln_g, ln_b, Wq, Wk, Wv, Wo,
                                        bq, bk, bv, xb, xm, wtqkv, wot, bqkv);
  qmkm_part<<<dim3(4,32,2), 256, 0, stream>>>(xm, Wq, Wk, part);
  qmkm_reduce<<<dim3(256,2), 256, 0, stream>>>(part, bq, bk, qm, km);
  topk_kernel<<<1024, 256, 0, stream>>>(qm, km, sel);
  gemm_bt<1,1><<<dim3(24,32), 256, 0, stream>>>(xb, wtqkv, bqkv, (void*)qkvb, 3072);
  attn_kernel<<<1024, 256, 0, stream>>>(qkvb, sel, ctx);
  gemm_bt64<<<dim3(16,32), 256, 0, stream>>>(ctx, wot, bo, (float*)d_out, 1024);
}

// Round 17
// 135.421 us; speedup vs baseline: 1.0433x; 1.0433x over previous
//
#include <hip/hip_runtime.h>
#include <stdint.h>

#define DEV static __device__ __forceinline__

typedef __attribute__((ext_vector_type(8))) short s16x8;   // 8 bf16 in 4 VGPRs
typedef __attribute__((ext_vector_type(4))) float f32x4;   // MFMA acc

// ---------- problem constants ----------
constexpr int Bdim = 2, Sdim = 2048, Ddim = 1024, Hdim = 16, DH = 64;
constexpr int Mrows = Bdim * Sdim;      // 4096
constexpr int NB = 32;                  // S / 64
constexpr int SEL_STRIDE = 18;          // [count, up to 17 block ids]

// Q prescale folded into QKV epilogue: 1/sqrt(64) * log2(e)
#define QSCALE 0.18033688011112042f
#define MFIX   8.0f                     // fixed softmax max (log2 domain, >=5 sigma margin)

// ---------- workspace layout (bytes) ----------
constexpr size_t OFF_XB    = 0;                                        // x bf16 [4096][1024]
constexpr size_t OFF_WTQKV = OFF_XB    + (size_t)Mrows*Ddim*2;         // Wqkv^T bf16 [3072][1024]
constexpr size_t OFF_WOT   = OFF_WTQKV + (size_t)3072*1024*2;          // Wo^T bf16 [1024][1024]
constexpr size_t OFF_QKV   = OFF_WOT   + (size_t)1024*1024*2;          // qkv bf16 [4096][3072]
constexpr size_t OFF_CTX   = OFF_QKV   + (size_t)Mrows*3072*2;         // ctx bf16 [4096][1024]
constexpr size_t OFF_XM    = OFF_CTX   + (size_t)Mrows*Ddim*2;         // xm f32 [64][1024]
constexpr size_t OFF_QM    = OFF_XM    + (size_t)64*1024*4;            // qm f32 [64][1024]
constexpr size_t OFF_KM    = OFF_QM    + (size_t)64*1024*4;            // km f32 [64][1024]
constexpr size_t OFF_BIASQ = OFF_KM    + (size_t)64*1024*4;            // f32 [3072]
constexpr size_t OFF_SEL   = OFF_BIASQ + (size_t)3072*4;               // int [1024][18]
constexpr size_t OFF_PART  = OFF_SEL   + (size_t)1024*SEL_STRIDE*4;    // f32 [2][8][64][1024]

DEV float bf2f(unsigned short u){ union{unsigned int i; float f;} x; x.i = ((unsigned int)u)<<16; return x.f; }
DEV unsigned short f2bf(float f){ union{float f; unsigned int i;} x; x.f=f;
  unsigned int r = x.i + 0x7fffu + ((x.i>>16)&1u); return (unsigned short)(r>>16); }

// global -> LDS async 16B (per-wave: lane l writes ldsbase + l*16)
DEV void gload16(const unsigned short* g, unsigned short* l){
  __builtin_amdgcn_global_load_lds(
      (__attribute__((address_space(1))) void*)(void*)g,
      (__attribute__((address_space(3))) void*)l, 16, 0, 0);
}

DEV unsigned int cvtpk(float a, float b){
  unsigned int r;
  asm("v_cvt_pk_bf16_f32 %0, %1, %2" : "=v"(r) : "v"(a), "v"(b));
  return r;
}

DEV float exp2fast(float x){           // D = 2^x (v_exp_f32 is natively base-2)
  float r;
  asm("v_exp_f32 %0, %1" : "=v"(r) : "v"(x));
  return r;
}

// =============================================================
// prep: fused {ln (blocks 0..4095), xm (4096..4159),
//              wtrans4+biascat (4160..8255)} — all input-only.
// =============================================================
__global__ __launch_bounds__(256) void prep_kernel(const float* __restrict__ inp,
                                                   const float* __restrict__ gam,
                                                   const float* __restrict__ bet,
                                                   const float* __restrict__ Wq,
                                                   const float* __restrict__ Wk,
                                                   const float* __restrict__ Wv,
                                                   const float* __restrict__ Wo,
                                                   const float* __restrict__ bq,
                                                   const float* __restrict__ bk,
                                                   const float* __restrict__ bv,
                                                   unsigned short* __restrict__ xb,
                                                   float* __restrict__ xm,
                                                   unsigned short* __restrict__ wtqkv,
                                                   unsigned short* __restrict__ wot,
                                                   float* __restrict__ bqkv){
  __shared__ float sh[4][1024];          // 16KB union for all three roles
  const int bid = blockIdx.x;
  const int t = threadIdx.x;

  if (bid < 4096){
    // ---------------- ln: one row ----------------
    const int row = bid;
    float* red = &sh[0][0];
    const float4 v = ((const float4*)(inp + (size_t)row*Ddim))[t];
    float s  = v.x + v.y + v.z + v.w;
    float s2 = v.x*v.x + v.y*v.y + v.z*v.z + v.w*v.w;
#pragma unroll
    for (int mk=32; mk>=1; mk>>=1){ s += __shfl_xor(s, mk); s2 += __shfl_xor(s2, mk); }
    if ((t&63)==0){ red[t>>6] = s; red[4+(t>>6)] = s2; }
    __syncthreads();
    s  = red[0]+red[1]+red[2]+red[3];
    s2 = red[4]+red[5]+red[6]+red[7];
    const float mu  = s * (1.f/Ddim);
    const float var = s2 * (1.f/Ddim) - mu*mu;
    const float rs  = rsqrtf(var + 1e-5f);
    const float4 gv = ((const float4*)gam)[t];
    const float4 bv2 = ((const float4*)bet)[t];
    float o0 = (v.x-mu)*rs*gv.x + bv2.x;
    float o1 = (v.y-mu)*rs*gv.y + bv2.y;
    float o2 = (v.z-mu)*rs*gv.z + bv2.z;
    float o3 = (v.w-mu)*rs*gv.w + bv2.w;
    uint2 u;
    u.x = (unsigned int)f2bf(o0) | ((unsigned int)f2bf(o1)<<16);
    u.y = (unsigned int)f2bf(o2) | ((unsigned int)f2bf(o3)<<16);
    ((uint2*)(xb + (size_t)row*Ddim))[t] = u;
  } else if (bid < 4160){
    // ---------------- xm: one 64-row block ----------------
    const int blk = bid - 4096;
    const int w = t>>6, lane = t&63;
    float4 gv[4], bvv[4];
#pragma unroll
    for (int p=0;p<4;++p){ gv[p] = ((const float4*)gam)[lane + 64*p];
                           bvv[p] = ((const float4*)bet)[lane + 64*p]; }
    float ax[4][4];
#pragma unroll
    for (int p=0;p<4;++p)
#pragma unroll
      for (int c=0;c<4;++c) ax[p][c]=0.f;
    for (int rr=0; rr<16; ++rr){
      const int row = blk*64 + w*16 + rr;
      const float4* rp = (const float4*)(inp + (size_t)row*Ddim);
      float4 v[4]; float s=0.f, s2=0.f;
#pragma unroll
      for (int p=0;p<4;++p){
        v[p] = rp[lane + 64*p];
        s  += v[p].x+v[p].y+v[p].z+v[p].w;
        s2 += v[p].x*v[p].x+v[p].y*v[p].y+v[p].z*v[p].z+v[p].w*v[p].w;
      }
#pragma unroll
      for (int mk=32; mk>=1; mk>>=1){ s += __shfl_xor(s,mk); s2 += __shfl_xor(s2,mk); }
      const float mu = s*(1.f/Ddim);
      const float var = s2*(1.f/Ddim) - mu*mu;
      const float rs = rsqrtf(var + 1e-5f);
#pragma unroll
      for (int p=0;p<4;++p){
        ax[p][0] += (v[p].x-mu)*rs*gv[p].x + bvv[p].x;
        ax[p][1] += (v[p].y-mu)*rs*gv[p].y + bvv[p].y;
        ax[p][2] += (v[p].z-mu)*rs*gv[p].z + bvv[p].z;
        ax[p][3] += (v[p].w-mu)*rs*gv[p].w + bvv[p].w;
      }
    }
#pragma unroll
    for (int p=0;p<4;++p){
      float4 o; o.x=ax[p][0]; o.y=ax[p][1]; o.z=ax[p][2]; o.w=ax[p][3];
      ((float4*)&sh[w][0])[lane + 64*p] = o;
    }
    __syncthreads();
    float4 r0 = ((float4*)&sh[0][0])[t];
    float4 r1 = ((float4*)&sh[1][0])[t];
    float4 r2 = ((float4*)&sh[2][0])[t];
    float4 r3 = ((float4*)&sh[3][0])[t];
    float4 o;
    o.x = (r0.x+r1.x+r2.x+r3.x)*(1.f/64);
    o.y = (r0.y+r1.y+r2.y+r3.y)*(1.f/64);
    o.z = (r0.z+r1.z+r2.z+r3.z)*(1.f/64);
    o.w = (r0.w+r1.w+r2.w+r3.w)*(1.f/64);
    ((float4*)(xm + (size_t)blk*Ddim))[t] = o;
  } else {
    // ---------------- wtrans: one 32x32 tile ----------------
    const int wt = bid - 4160;
    const int z = wt >> 10, rem = wt & 1023;
    const int bx = rem & 31, by = rem >> 5;
    const float* W = (z==0)?Wq:(z==1)?Wk:(z==2)?Wv:Wo;
    unsigned short* Wt = (z<3) ? (wtqkv + (size_t)z*1024*1024) : wot;
    const int n0 = bx*32, k0 = by*32;
    const int r = t>>5, c = t&31;
    float (*tile)[33] = (float(*)[33])&sh[0][0];
    if (z<3 && bx==0 && by==0){
      const float* bb = (z==0)?bq:(z==1)?bk:bv;
#pragma unroll
      for (int i=0;i<4;++i) bqkv[z*1024 + t + 256*i] = bb[t + 256*i];
    }
#pragma unroll
    for (int i=0;i<4;++i) tile[r+8*i][c] = W[(size_t)(k0 + r + 8*i)*1024 + n0 + c];
    __syncthreads();
    const int nr = t >> 3, kq = (t & 7) * 4;
    unsigned int w0 = (unsigned int)f2bf(tile[kq  ][nr]) | ((unsigned int)f2bf(tile[kq+1][nr])<<16);
    unsigned int w1 = (unsigned int)f2bf(tile[kq+2][nr]) | ((unsigned int)f2bf(tile[kq+3][nr])<<16);
    uint2 st; st.x = w0; st.y = w1;
    *(uint2*)&Wt[(size_t)(n0 + nr)*1024 + k0 + kq] = st;
  }
}

// =============================================================
// qm/km partials: k-split exact fp32 GEMM (round-5 proven version)
// =============================================================
__global__ __launch_bounds__(256) void qmkm_part(const float* __restrict__ xm,
    const float* __restrict__ Wq, const float* __restrict__ Wk,
    float* __restrict__ part){
  const int c  = blockIdx.x*256 + threadIdx.x;
  const int rg = blockIdx.y >> 3, ks = blockIdx.y & 7;
  const int z  = blockIdx.z;
  const float* W = z ? Wk : Wq;
  const int r0 = rg*16, k0 = ks*128;
  float acc[16];
#pragma unroll
  for (int r=0;r<16;++r) acc[r]=0.f;
  for (int k=0;k<128;k+=4){
    const float wv0 = W[(size_t)(k0+k  )*1024 + c];
    const float wv1 = W[(size_t)(k0+k+1)*1024 + c];
    const float wv2 = W[(size_t)(k0+k+2)*1024 + c];
    const float wv3 = W[(size_t)(k0+k+3)*1024 + c];
#pragma unroll
    for (int r=0;r<16;++r){
      const float4 xv = *(const float4*)&xm[(size_t)(r0+r)*1024 + k0 + k];
      acc[r] = fmaf(xv.w, wv3, fmaf(xv.z, wv2, fmaf(xv.y, wv1, fmaf(xv.x, wv0, acc[r]))));
    }
  }
  float* dst = part + (((size_t)z*8 + ks)*64 + r0)*1024 + c;
#pragma unroll
  for (int r=0;r<16;++r) dst[(size_t)r*1024] = acc[r];
}

__global__ __launch_bounds__(256) void qmkm_reduce(const float* __restrict__ part,
    const float* __restrict__ bq, const float* __restrict__ bk,
    float* __restrict__ qm, float* __restrict__ km){
  const int idx = blockIdx.x*256 + threadIdx.x;
  const int z = blockIdx.y;
  const int c = idx & 1023, r = idx >> 10;
  const float* p = part + ((size_t)z*8*64*1024) + (size_t)r*1024 + c;
  float s = 0.f;
#pragma unroll
  for (int ks=0; ks<8; ++ks) s += p[(size_t)ks*64*1024];
  s += z ? bk[c] : bq[c];
  (z ? km : qm)[(size_t)r*1024 + c] = s;
}

// =============================================================
// block similarity + top-16 selection (matches jax.lax.top_k ties)
// =============================================================
__global__ __launch_bounds__(256) void topk_kernel(const float* __restrict__ qm,
                                                   const float* __restrict__ km,
                                                   int* __restrict__ sel){
  const int bhq = blockIdx.x;
  const int qb = bhq & 31, h = (bhq>>5) & 15, b = bhq >> 9;
  const int t = threadIdx.x;
  __shared__ float sim[32];
  __shared__ int keep[32];
  const int kb = t>>3, l8 = t&7;
  float acc = 0.f;
  if (kb <= qb){
    const float* qv = qm + (size_t)(b*32 + qb)*1024 + h*64;
    const float* kv = km + (size_t)(b*32 + kb)*1024 + h*64;
#pragma unroll
    for (int d=0; d<8; ++d) acc += qv[l8*8+d] * kv[l8*8+d];
  }
  acc += __shfl_xor(acc,1); acc += __shfl_xor(acc,2); acc += __shfl_xor(acc,4);
  if (l8==0) sim[kb] = (kb<=qb) ? acc : -1e30f;
  __syncthreads();
  if (t < 32){
    int k2 = t; int ok = 0;
    if (k2 <= qb){
      float sv = sim[k2]; int rank = 0;
      for (int j=0;j<=qb;++j){
        float sj = sim[j];
        rank += (sj > sv) || (sj == sv && j < k2);
      }
      ok = (rank < 16) || (k2 == qb);
    }
    keep[t] = ok;
  }
  __syncthreads();
  if (t == 0){
    int* dstp = sel + (size_t)bhq * SEL_STRIDE;
    int c = 0;
    for (int j=0;j<32;++j) if (keep[j]) dstp[1+c++] = j;
    dstp[0] = c;
  }
}

// =============================================================
// bf16 MFMA GEMM (QKV): 128x128, BK=32 TRIPLE-BUFFERED depth-2
// pipeline (vmcnt(8) steady state). 2-D XCD partition. SCALEQ folds
// attn's log2-domain Q prescale into the epilogue. (proven r12)
// =============================================================
#define G_STAGE(bsel, kofs) do { \
  gload16(A0 + (kofs), ldsA + (bsel)*4096 + (wid*2+0)*512); \
  gload16(A1 + (kofs), ldsA + (bsel)*4096 + (wid*2+1)*512); \
  gload16(B0 + (kofs), ldsB + (bsel)*4096 + (wid*2+0)*512); \
  gload16(B1 + (kofs), ldsB + (bsel)*4096 + (wid*2+1)*512); \
} while(0)

#define G_COMPUTE(bsel) do { \
  s16x8 af[4], bfr[4]; \
  _Pragma("unroll") \
  for (int mi=0;mi<4;++mi){ \
    int row = wr*64 + mi*16 + rl; \
    af[mi] = *(const s16x8*)((char*)ldsA + (bsel)*8192 + row*64 + ((g ^ ((row>>1)&3))<<4)); \
  } \
  _Pragma("unroll") \
  for (int ni=0;ni<4;++ni){ \
    int row = wc*64 + ni*16 + rl; \
    bfr[ni] = *(const s16x8*)((char*)ldsB + (bsel)*8192 + row*64 + ((g ^ ((row>>1)&3))<<4)); \
  } \
  _Pragma("unroll") \
  for (int mi=0;mi<4;++mi) \
    _Pragma("unroll") \
    for (int ni=0;ni<4;++ni) \
      acc[mi][ni] = __builtin_amdgcn_mfma_f32_16x16x32_bf16(af[mi], bfr[ni], acc[mi][ni], 0,0,0); \
} while(0)

template<int OUT_BF16, int SCALEQ>
__global__ __launch_bounds__(256) void gemm_bt(const unsigned short* __restrict__ A,
                                               const unsigned short* __restrict__ Bt,
                                               const float* __restrict__ bias,
                                               void* __restrict__ C, int N){
  constexpr int K = 1024;
  constexpr int NT = K/32;                          // 32 K-tiles
  __shared__ unsigned short ldsA[3*128*32];
  __shared__ unsigned short ldsB[3*128*32];
  const int t = threadIdx.x, lane = t & 63, wid = t >> 6;
  const int wr = wid >> 1, wc = wid & 1;
  const int rl = lane & 15, g = lane >> 4;

  const int nbx = gridDim.x, nby = gridDim.y;
  const int id  = blockIdx.y * nbx + blockIdx.x;
  const int xcd = id & 7, j = id >> 3;
  const int MBP = nby >> 2, NBP = nbx >> 1;
  const int mg = xcd >> 1, ng = xcd & 1;
  const int m0 = (mg*MBP + (j % MBP)) * 128;
  const int n0 = (ng*NBP + (j / MBP)) * 128;

  const f32x4 ZERO4 = {0.f,0.f,0.f,0.f};
  f32x4 acc[4][4];
#pragma unroll
  for (int i=0;i<4;++i)
#pragma unroll
    for (int j2=0;j2<4;++j2) acc[i][j2] = ZERO4;

  const int slot0 = wid*128 + lane, slot1 = slot0 + 64;
  const int sr0 = slot0>>2, sc0 = slot0&3;
  const int sr1 = slot1>>2, sc1 = slot1&3;
  const unsigned short* A0 = A  + (size_t)(m0 + sr0)*K + (sc0 ^ ((sr0>>1)&3))*8;
  const unsigned short* A1 = A  + (size_t)(m0 + sr1)*K + (sc1 ^ ((sr1>>1)&3))*8;
  const unsigned short* B0 = Bt + (size_t)(n0 + sr0)*K + (sc0 ^ ((sr0>>1)&3))*8;
  const unsigned short* B1 = Bt + (size_t)(n0 + sr1)*K + (sc1 ^ ((sr1>>1)&3))*8;

  G_STAGE(0, 0);
  G_STAGE(1, 32);

  for (int ti=0; ti<NT; ++ti){
    const int cur = ti % 3;
    if (ti+2 < NT){
      G_STAGE((ti+2)%3, (ti+2)*32);
      asm volatile("s_waitcnt vmcnt(8)" ::: "memory");
    } else if (ti+1 < NT){
      asm volatile("s_waitcnt vmcnt(4)" ::: "memory");
    } else {
      asm volatile("s_waitcnt vmcnt(0)" ::: "memory");
    }
    __builtin_amdgcn_s_barrier();
    __builtin_amdgcn_sched_barrier(0);
    G_COMPUTE(cur);
    __builtin_amdgcn_sched_barrier(0);
    __builtin_amdgcn_s_barrier();
  }

  const int r4 = g*4;
#pragma unroll
  for (int mi=0;mi<4;++mi){
#pragma unroll
    for (int ni=0;ni<4;++ni){
      int col = n0 + wc*64 + ni*16 + rl;
      float bb = bias[col];
      float sc = (SCALEQ && col < 1024) ? QSCALE : 1.0f;
#pragma unroll
      for (int e=0;e<4;++e){
        int row = m0 + wr*64 + mi*16 + r4 + e;
        float v = (acc[mi][ni][e] + bb) * sc;
        if (OUT_BF16) ((unsigned short*)C)[(size_t)row*N + col] = f2bf(v);
        else          ((float*)C)[(size_t)row*N + col] = v;
      }
    }
  }
}

// =============================================================
// O-proj GEMM: 128x64 tile, BK=32 triple-buffer counted-vmcnt
// pipeline (vmcnt(6) steady). (proven r15)
// =============================================================
#define G64_STAGE(bsel, kofs) do { \
  gload16(A0 + (kofs), ldsA + (bsel)*4096 + (wid*2+0)*512); \
  gload16(A1 + (kofs), ldsA + (bsel)*4096 + (wid*2+1)*512); \
  gload16(B0 + (kofs), ldsB + (bsel)*2048 + wid*512); \
} while(0)

#define G64_COMPUTE(bsel) do { \
  s16x8 af[4], bfr[2]; \
  _Pragma("unroll") \
  for (int mi=0;mi<4;++mi){ \
    int row = wr*64 + mi*16 + rl; \
    af[mi] = *(const s16x8*)((char*)ldsA + (bsel)*8192 + row*64 + ((g ^ ((row>>1)&3))<<4)); \
  } \
  _Pragma("unroll") \
  for (int ni=0;ni<2;++ni){ \
    int row = wc*32 + ni*16 + rl; \
    bfr[ni] = *(const s16x8*)((char*)ldsB + (bsel)*4096 + row*64 + ((g ^ ((row>>1)&3))<<4)); \
  } \
  _Pragma("unroll") \
  for (int mi=0;mi<4;++mi) \
    _Pragma("unroll") \
    for (int ni=0;ni<2;++ni) \
      acc[mi][ni] = __builtin_amdgcn_mfma_f32_16x16x32_bf16(af[mi], bfr[ni], acc[mi][ni], 0,0,0); \
} while(0)

__global__ __launch_bounds__(256) void gemm_bt64(const unsigned short* __restrict__ A,
                                                 const unsigned short* __restrict__ Bt,
                                                 const float* __restrict__ bias,
                                                 float* __restrict__ C, int N){
  constexpr int K = 1024;
  constexpr int NT = K/32;
  __shared__ unsigned short ldsA[3*128*32];
  __shared__ unsigned short ldsB[3*64*32];
  const int t = threadIdx.x, lane = t & 63, wid = t >> 6;
  const int wr = wid >> 1, wc = wid & 1;
  const int rl = lane & 15, g = lane >> 4;

  const int id  = blockIdx.y * gridDim.x + blockIdx.x;
  const int xcd = id & 7, j = id >> 3;            // j 0..63
  const int mg = xcd >> 1, ng = xcd & 1;
  const int m0 = (mg*8 + (j & 7)) * 128;          // 32 m-blocks
  const int n0 = (ng*8 + (j >> 3)) * 64;          // 16 n-blocks

  const f32x4 ZERO4 = {0.f,0.f,0.f,0.f};
  f32x4 acc[4][2];
#pragma unroll
  for (int i=0;i<4;++i)
#pragma unroll
    for (int j2=0;j2<2;++j2) acc[i][j2] = ZERO4;

  const int slot0 = wid*128 + lane, slot1 = slot0 + 64;
  const int sr0 = slot0>>2, sc0 = slot0&3;
  const int sr1 = slot1>>2, sc1 = slot1&3;
  const unsigned short* A0 = A + (size_t)(m0 + sr0)*K + (sc0 ^ ((sr0>>1)&3))*8;
  const unsigned short* A1 = A + (size_t)(m0 + sr1)*K + (sc1 ^ ((sr1>>1)&3))*8;
  const int slotB = wid*64 + lane;
  const int srB = slotB>>2, scB = slotB&3;
  const unsigned short* B0 = Bt + (size_t)(n0 + srB)*K + (scB ^ ((srB>>1)&3))*8;

  G64_STAGE(0, 0);
  G64_STAGE(1, 32);

  for (int ti=0; ti<NT; ++ti){
    const int cur = ti % 3;
    if (ti+2 < NT){
      G64_STAGE((ti+2)%3, (ti+2)*32);
      asm volatile("s_waitcnt vmcnt(6)" ::: "memory");
    } else if (ti+1 < NT){
      asm volatile("s_waitcnt vmcnt(3)" ::: "memory");
    } else {
      asm volatile("s_waitcnt vmcnt(0)" ::: "memory");
    }
    __builtin_amdgcn_s_barrier();
    __builtin_amdgcn_sched_barrier(0);
    G64_COMPUTE(cur);
    __builtin_amdgcn_sched_barrier(0);
    __builtin_amdgcn_s_barrier();
  }

  const int r4 = g*4;
#pragma unroll
  for (int mi=0;mi<4;++mi){
#pragma unroll
    for (int ni=0;ni<2;++ni){
      int col = n0 + wc*32 + ni*16 + rl;
      float bb = bias[col];
#pragma unroll
      for (int e=0;e<4;++e){
        int row = m0 + wr*64 + mi*16 + r4 + e;
        C[(size_t)row*N + col] = acc[mi][ni][e] + bb;
      }
    }
  }
}

// =============================================================
// Sparse flash attention v6 (proven best): FIXED-MAX softmax —
// p = exp2(S - 8). Q prescaled (log2 domain) in the QKV GEMM
// epilogue. Lane-local P rows; cvtpk + ds_bpermute redistribution;
// O^T = V^T*P^T; double-buffered K/V reg prefetch; PAIRED balanced
// blocks (each exactly 17 iters) + XCD pinning; setprio on MFMA.
// =============================================================
__global__ __launch_bounds__(256) void attn_kernel(const unsigned short* __restrict__ qkv,
                                                   const int* __restrict__ sel,
                                                   unsigned short* __restrict__ ctx){
  const int id = blockIdx.x;                 // 0..767
  const int xcd = id & 7, jj = id >> 3;      // jj 0..95
  const int bh = xcd + 8*(jj/24);
  const int tau = jj % 24;
  const int h = bh & 15, b = bh >> 4;
  int qbl[2]; int nq;
  if (tau < 8){ qbl[0]=tau; qbl[1]=15-tau; nq=2; }
  else        { qbl[0]=tau+8; qbl[1]=0;    nq=1; }

  const int t = threadIdx.x, wid = t >> 6, lane = t & 63;
  const int rl = lane & 15, g = lane >> 4;
  const int q_local = wid*16 + rl;

  __shared__ unsigned short K_s[2][4096];    // [j 64][128B], chunk^(j&7) swizzle
  __shared__ unsigned short V_s[2][4096];    // V^T [d 64][128B], chunk^((d&7)^(d>>3))

  const int jst = t >> 2, cq = t & 3;        // K: row jst, chunks 2cq, 2cq+1
  const int r2 = t >> 3, dq = t & 7;         // V: rows 2r2,2r2+1, d-base dq*8
  const unsigned short* kbase = qkv + (size_t)(b*Sdim + jst)*3072 + 1024 + h*DH + cq*16;
  const unsigned short* vbase = qkv + (size_t)(b*Sdim + 2*r2)*3072 + 2048 + h*DH + dq*8;
  const int kwb0 = jst*128 + (((cq*2  ) ^ (jst&7))<<4);
  const int kwb1 = jst*128 + (((cq*2+1) ^ (jst&7))<<4);
  const f32x4 ZERO4 = {0.f,0.f,0.f,0.f};

  const int src0 = (rl + 16*((2*g  ) & 3)) << 2;
  const int src1 = (rl + 16*((2*g+1) & 3)) << 2;
  const bool hsel = (g >> 1);

  for (int iq=0; iq<nq; ++iq){
    const int qb = qbl[iq];
    const int* selrow = sel + (size_t)(((b*Hdim)+h)*NB + qb) * SEL_STRIDE;
    const int ns = selrow[0];

    const int qg0 = b*Sdim + qb*64 + q_local;
    const unsigned short* qbase = qkv + (size_t)qg0*3072 + h*DH;
    s16x8 qa[2];                 // raw loads — prescale done in GEMM epilogue
    qa[0] = *(const s16x8*)(qbase + g*8);
    qa[1] = *(const s16x8*)(qbase + 32 + g*8);

    f32x4 o[4];                  // O^T: o[f][e] = O[q=q_local][d = f*16 + g*4 + e]
    float l_p = 0.f;             // per-lane partial denominator
#pragma unroll
    for (int f=0; f<4; ++f) o[f] = ZERO4;

    __syncthreads();            // bufs free of prev-qb readers

    int kb = selrow[1];
    s16x8 kr0, kr1, vr0, vr1;
    {
      const size_t off = (size_t)kb*64*3072;
      kr0 = *(const s16x8*)(kbase + off);
      kr1 = *(const s16x8*)(kbase + off + 8);
      vr0 = *(const s16x8*)(vbase + off);
      vr1 = *(const s16x8*)(vbase + off + 3072);
    }

    for (int it=0; it<ns; ++it){
      const int buf = it & 1;
      unsigned short* Kw = &K_s[buf][0];
      unsigned short* Vw = &V_s[buf][0];
      *(s16x8*)((char*)Kw + kwb0) = kr0;
      *(s16x8*)((char*)Kw + kwb1) = kr1;
#pragma unroll
      for (int e=0;e<8;++e){
        const int d1 = dq*8 + e;
        const int sw = (d1&7) ^ (d1>>3);
        const unsigned int pr = (unsigned int)(unsigned short)vr0[e]
                              | ((unsigned int)(unsigned short)vr1[e] << 16);
        *(unsigned int*)((char*)Vw + d1*128 + ((4*r2) ^ (sw<<4))) = pr;
      }
      const int kbcur = kb;
      if (it+1 < ns){
        kb = selrow[2+it];
        const size_t off = (size_t)kb*64*3072;
        kr0 = *(const s16x8*)(kbase + off);
        kr1 = *(const s16x8*)(kbase + off + 8);
        vr0 = *(const s16x8*)(vbase + off);
        vr1 = *(const s16x8*)(vbase + off + 3072);
      }
      __syncthreads();

      // ---- S^T = K Q'^T  (log2 domain via Q prescale) ----
      f32x4 sfT[4];
#pragma unroll
      for (int f=0;f<4;++f) sfT[f] = ZERO4;
      __builtin_amdgcn_s_setprio(1);
#pragma unroll
      for (int kk=0;kk<2;++kk){
#pragma unroll
        for (int f=0;f<4;++f){
          const int jr = f*16 + rl;
          s16x8 kf = *(const s16x8*)((char*)Kw + jr*128 + (((kk*4+g) ^ (jr&7))<<4));
          sfT[f] = __builtin_amdgcn_mfma_f32_16x16x32_bf16(kf, qa[kk], sfT[f], 0,0,0);
        }
      }
      __builtin_amdgcn_s_setprio(0);
      if (kbcur == qb){
#pragma unroll
        for (int f=0;f<4;++f)
#pragma unroll
          for (int e=0;e<4;++e){
            const int j2 = f*16 + g*4 + e;
            if (j2 > q_local) sfT[f][e] = -1e9f;
          }
      }
      // ---- fixed-max softmax weights: p = 2^(S - MFIX) ----
      {
        float rs = 0.f;
#pragma unroll
        for (int f=0;f<4;++f)
#pragma unroll
          for (int e=0;e<4;++e){
            const float p = exp2fast(sfT[f][e] - MFIX);
            sfT[f][e] = p; rs += p;
          }
        l_p += rs;
      }

      unsigned int plo[4], phi[4];
#pragma unroll
      for (int f=0;f<4;++f){
        plo[f] = cvtpk(sfT[f][0], sfT[f][1]);
        phi[f] = cvtpk(sfT[f][2], sfT[f][3]);
      }

#pragma unroll
      for (int kk=0;kk<2;++kk){
        const int f0 = 2*kk, f1 = 2*kk+1;
        unsigned int a0, b0, w0, w1, w2, w3;
        a0 = __builtin_amdgcn_ds_bpermute(src0, plo[f0]);
        b0 = __builtin_amdgcn_ds_bpermute(src0, plo[f1]);
        w0 = hsel ? b0 : a0;
        a0 = __builtin_amdgcn_ds_bpermute(src0, phi[f0]);
        b0 = __builtin_amdgcn_ds_bpermute(src0, phi[f1]);
        w1 = hsel ? b0 : a0;
        a0 = __builtin_amdgcn_ds_bpermute(src1, plo[f0]);
        b0 = __builtin_amdgcn_ds_bpermute(src1, plo[f1]);
        w2 = hsel ? b0 : a0;
        a0 = __builtin_amdgcn_ds_bpermute(src1, phi[f0]);
        b0 = __builtin_amdgcn_ds_bpermute(src1, phi[f1]);
        w3 = hsel ? b0 : a0;
        union { unsigned int u[4]; s16x8 v; } pfc;
        pfc.u[0] = w0; pfc.u[1] = w1; pfc.u[2] = w2; pfc.u[3] = w3;
        const s16x8 pf = pfc.v;
        __builtin_amdgcn_s_setprio(1);
#pragma unroll
        for (int f=0;f<4;++f){
          const int d = f*16 + rl;
          const int sw = (d&7) ^ (d>>3);
          s16x8 vf = *(const s16x8*)((char*)Vw + d*128 + ((64*kk + 16*g) ^ (sw<<4)));
          o[f] = __builtin_amdgcn_mfma_f32_16x16x32_bf16(vf, pf, o[f], 0,0,0);
        }
        __builtin_amdgcn_s_setprio(0);
      }
    }

    {
      float l_r = l_p;
      l_r += __shfl_xor(l_r, 16);
      l_r += __shfl_xor(l_r, 32);
      const float inv = 1.f / l_r;
      unsigned short* crow = ctx + (size_t)qg0*Ddim + h*DH;
#pragma unroll
      for (int f=0;f<4;++f){
        uint2 st;
        st.x = (unsigned int)f2bf(o[f][0]*inv) | ((unsigned int)f2bf(o[f][1]*inv)<<16);
        st.y = (unsigned int)f2bf(o[f][2]*inv) | ((unsigned int)f2bf(o[f][3]*inv)<<16);
        *(uint2*)(crow + f*16 + g*4) = st;
      }
    }
  }
}

// =============================================================
extern "C" void kernel_launch(void* const* d_in, const int* in_sizes, int n_in,
                              void* d_out, int out_size, void* d_ws, size_t ws_size,
                              hipStream_t stream){
  (void)in_sizes; (void)n_in; (void)out_size; (void)ws_size;
  const float* inp  = (const float*)d_in[0];
  const float* ln_g = (const float*)d_in[1];
  const float* ln_b = (const float*)d_in[2];
  const float* Wq   = (const float*)d_in[3];
  const float* bq   = (const float*)d_in[4];
  const float* Wk   = (const float*)d_in[5];
  const float* bk   = (const float*)d_in[6];
  const float* Wv   = (const float*)d_in[7];
  const float* bv   = (const float*)d_in[8];
  const float* Wo   = (const float*)d_in[9];
  const float* bo   = (const float*)d_in[10];

  char* ws = (char*)d_ws;
  unsigned short* xb    = (unsigned short*)(ws + OFF_XB);
  unsigned short* wtqkv = (unsigned short*)(ws + OFF_WTQKV);
  unsigned short* wot   = (unsigned short*)(ws + OFF_WOT);
  unsigned short* qkvb  = (unsigned short*)(ws + OFF_QKV);
  unsigned short* ctx   = (unsigned short*)(ws + OFF_CTX);
  float* xm   = (float*)(ws + OFF_XM);
  float* qm   = (float*)(ws + OFF_QM);
  float* km   = (float*)(ws + OFF_KM);
  float* bqkv = (float*)(ws + OFF_BIASQ);
  int*   sel  = (int*)(ws + OFF_SEL);
  float* part = (float*)(ws + OFF_PART);

  prep_kernel<<<8256, 256, 0, stream>>>(inp, ln_g, ln_b, Wq, Wk, Wv, Wo,
                                        bq, bk, bv, xb, xm, wtqkv, wot, bqkv);
  qmkm_part<<<dim3(4,32,2), 256, 0, stream>>>(xm, Wq, Wk, part);
  qmkm_reduce<<<dim3(256,2), 256, 0, stream>>>(part, bq, bk, qm, km);
  topk_kernel<<<1024, 256, 0, stream>>>(qm, km, sel);
  gemm_bt<1,1><<<dim3(24,32), 256, 0, stream>>>(xb, wtqkv, bqkv, (void*)qkvb, 3072);
  attn_kernel<<<768, 256, 0, stream>>>(qkvb, sel, ctx);
  gemm_bt64<<<dim3(16,32), 256, 0, stream>>>(ctx, wot, bo, (float*)d_out, 1024);
}

// Round 18
// 134.714 us; speedup vs baseline: 1.0488x; 1.0052x over previous
//
#include <hip/hip_runtime.h>
#include <stdint.h>

#define DEV static __device__ __forceinline__

typedef __attribute__((ext_vector_type(8))) short s16x8;   // 8 bf16 in 4 VGPRs
typedef __attribute__((ext_vector_type(4))) float f32x4;   // MFMA acc

// ---------- problem constants ----------
constexpr int Bdim = 2, Sdim = 2048, Ddim = 1024, Hdim = 16, DH = 64;
constexpr int Mrows = Bdim * Sdim;      // 4096
constexpr int NB = 32;                  // S / 64

// Q prescale folded into QKV epilogue: 1/sqrt(64) * log2(e)
#define QSCALE 0.18033688011112042f
#define MFIX   8.0f                     // fixed softmax max (log2 domain, >=5 sigma margin)

// ---------- workspace layout (bytes) ----------
constexpr size_t OFF_XB    = 0;                                        // x bf16 [4096][1024]
constexpr size_t OFF_WTQKV = OFF_XB    + (size_t)Mrows*Ddim*2;         // Wqkv^T bf16 [3072][1024]
constexpr size_t OFF_WOT   = OFF_WTQKV + (size_t)3072*1024*2;          // Wo^T bf16 [1024][1024]
constexpr size_t OFF_QKV   = OFF_WOT   + (size_t)1024*1024*2;          // qkv bf16 [4096][3072]
constexpr size_t OFF_CTX   = OFF_QKV   + (size_t)Mrows*3072*2;         // ctx bf16 [4096][1024]
constexpr size_t OFF_XM    = OFF_CTX   + (size_t)Mrows*Ddim*2;         // xm f32 [64][1024]
constexpr size_t OFF_QM    = OFF_XM    + (size_t)64*1024*4;            // qm f32 [64][1024]
constexpr size_t OFF_KM    = OFF_QM    + (size_t)64*1024*4;            // km f32 [64][1024]
constexpr size_t OFF_BIASQ = OFF_KM    + (size_t)64*1024*4;            // f32 [3072]
constexpr size_t OFF_PART  = OFF_BIASQ + (size_t)3072*4;               // f32 [2][8][64][1024]

DEV float bf2f(unsigned short u){ union{unsigned int i; float f;} x; x.i = ((unsigned int)u)<<16; return x.f; }
DEV unsigned short f2bf(float f){ union{float f; unsigned int i;} x; x.f=f;
  unsigned int r = x.i + 0x7fffu + ((x.i>>16)&1u); return (unsigned short)(r>>16); }

// global -> LDS async 16B (per-wave: lane l writes ldsbase + l*16)
DEV void gload16(const unsigned short* g, unsigned short* l){
  __builtin_amdgcn_global_load_lds(
      (__attribute__((address_space(1))) void*)(void*)g,
      (__attribute__((address_space(3))) void*)l, 16, 0, 0);
}

DEV unsigned int cvtpk(float a, float b){
  unsigned int r;
  asm("v_cvt_pk_bf16_f32 %0, %1, %2" : "=v"(r) : "v"(a), "v"(b));
  return r;
}

DEV float exp2fast(float x){           // D = 2^x (v_exp_f32 is natively base-2)
  float r;
  asm("v_exp_f32 %0, %1" : "=v"(r) : "v"(x));
  return r;
}

// =============================================================
// prep: fused {ln (blocks 0..4095), xm (4096..4159),
//              wtrans4+biascat (4160..8255)} — all input-only.
// =============================================================
__global__ __launch_bounds__(256) void prep_kernel(const float* __restrict__ inp,
                                                   const float* __restrict__ gam,
                                                   const float* __restrict__ bet,
                                                   const float* __restrict__ Wq,
                                                   const float* __restrict__ Wk,
                                                   const float* __restrict__ Wv,
                                                   const float* __restrict__ Wo,
                                                   const float* __restrict__ bq,
                                                   const float* __restrict__ bk,
                                                   const float* __restrict__ bv,
                                                   unsigned short* __restrict__ xb,
                                                   float* __restrict__ xm,
                                                   unsigned short* __restrict__ wtqkv,
                                                   unsigned short* __restrict__ wot,
                                                   float* __restrict__ bqkv){
  __shared__ float sh[4][1024];          // 16KB union for all three roles
  const int bid = blockIdx.x;
  const int t = threadIdx.x;

  if (bid < 4096){
    // ---------------- ln: one row ----------------
    const int row = bid;
    float* red = &sh[0][0];
    const float4 v = ((const float4*)(inp + (size_t)row*Ddim))[t];
    float s  = v.x + v.y + v.z + v.w;
    float s2 = v.x*v.x + v.y*v.y + v.z*v.z + v.w*v.w;
#pragma unroll
    for (int mk=32; mk>=1; mk>>=1){ s += __shfl_xor(s, mk); s2 += __shfl_xor(s2, mk); }
    if ((t&63)==0){ red[t>>6] = s; red[4+(t>>6)] = s2; }
    __syncthreads();
    s  = red[0]+red[1]+red[2]+red[3];
    s2 = red[4]+red[5]+red[6]+red[7];
    const float mu  = s * (1.f/Ddim);
    const float var = s2 * (1.f/Ddim) - mu*mu;
    const float rs  = rsqrtf(var + 1e-5f);
    const float4 gv = ((const float4*)gam)[t];
    const float4 bv2 = ((const float4*)bet)[t];
    float o0 = (v.x-mu)*rs*gv.x + bv2.x;
    float o1 = (v.y-mu)*rs*gv.y + bv2.y;
    float o2 = (v.z-mu)*rs*gv.z + bv2.z;
    float o3 = (v.w-mu)*rs*gv.w + bv2.w;
    uint2 u;
    u.x = (unsigned int)f2bf(o0) | ((unsigned int)f2bf(o1)<<16);
    u.y = (unsigned int)f2bf(o2) | ((unsigned int)f2bf(o3)<<16);
    ((uint2*)(xb + (size_t)row*Ddim))[t] = u;
  } else if (bid < 4160){
    // ---------------- xm: one 64-row block ----------------
    const int blk = bid - 4096;
    const int w = t>>6, lane = t&63;
    float4 gv[4], bvv[4];
#pragma unroll
    for (int p=0;p<4;++p){ gv[p] = ((const float4*)gam)[lane + 64*p];
                           bvv[p] = ((const float4*)bet)[lane + 64*p]; }
    float ax[4][4];
#pragma unroll
    for (int p=0;p<4;++p)
#pragma unroll
      for (int c=0;c<4;++c) ax[p][c]=0.f;
    for (int rr=0; rr<16; ++rr){
      const int row = blk*64 + w*16 + rr;
      const float4* rp = (const float4*)(inp + (size_t)row*Ddim);
      float4 v[4]; float s=0.f, s2=0.f;
#pragma unroll
      for (int p=0;p<4;++p){
        v[p] = rp[lane + 64*p];
        s  += v[p].x+v[p].y+v[p].z+v[p].w;
        s2 += v[p].x*v[p].x+v[p].y*v[p].y+v[p].z*v[p].z+v[p].w*v[p].w;
      }
#pragma unroll
      for (int mk=32; mk>=1; mk>>=1){ s += __shfl_xor(s,mk); s2 += __shfl_xor(s2,mk); }
      const float mu = s*(1.f/Ddim);
      const float var = s2*(1.f/Ddim) - mu*mu;
      const float rs = rsqrtf(var + 1e-5f);
#pragma unroll
      for (int p=0;p<4;++p){
        ax[p][0] += (v[p].x-mu)*rs*gv[p].x + bvv[p].x;
        ax[p][1] += (v[p].y-mu)*rs*gv[p].y + bvv[p].y;
        ax[p][2] += (v[p].z-mu)*rs*gv[p].z + bvv[p].z;
        ax[p][3] += (v[p].w-mu)*rs*gv[p].w + bvv[p].w;
      }
    }
#pragma unroll
    for (int p=0;p<4;++p){
      float4 o; o.x=ax[p][0]; o.y=ax[p][1]; o.z=ax[p][2]; o.w=ax[p][3];
      ((float4*)&sh[w][0])[lane + 64*p] = o;
    }
    __syncthreads();
    float4 r0 = ((float4*)&sh[0][0])[t];
    float4 r1 = ((float4*)&sh[1][0])[t];
    float4 r2 = ((float4*)&sh[2][0])[t];
    float4 r3 = ((float4*)&sh[3][0])[t];
    float4 o;
    o.x = (r0.x+r1.x+r2.x+r3.x)*(1.f/64);
    o.y = (r0.y+r1.y+r2.y+r3.y)*(1.f/64);
    o.z = (r0.z+r1.z+r2.z+r3.z)*(1.f/64);
    o.w = (r0.w+r1.w+r2.w+r3.w)*(1.f/64);
    ((float4*)(xm + (size_t)blk*Ddim))[t] = o;
  } else {
    // ---------------- wtrans: one 32x32 tile ----------------
    const int wt = bid - 4160;
    const int z = wt >> 10, rem = wt & 1023;
    const int bx = rem & 31, by = rem >> 5;
    const float* W = (z==0)?Wq:(z==1)?Wk:(z==2)?Wv:Wo;
    unsigned short* Wt = (z<3) ? (wtqkv + (size_t)z*1024*1024) : wot;
    const int n0 = bx*32, k0 = by*32;
    const int r = t>>5, c = t&31;
    float (*tile)[33] = (float(*)[33])&sh[0][0];
    if (z<3 && bx==0 && by==0){
      const float* bb = (z==0)?bq:(z==1)?bk:bv;
#pragma unroll
      for (int i=0;i<4;++i) bqkv[z*1024 + t + 256*i] = bb[t + 256*i];
    }
#pragma unroll
    for (int i=0;i<4;++i) tile[r+8*i][c] = W[(size_t)(k0 + r + 8*i)*1024 + n0 + c];
    __syncthreads();
    const int nr = t >> 3, kq = (t & 7) * 4;
    unsigned int w0 = (unsigned int)f2bf(tile[kq  ][nr]) | ((unsigned int)f2bf(tile[kq+1][nr])<<16);
    unsigned int w1 = (unsigned int)f2bf(tile[kq+2][nr]) | ((unsigned int)f2bf(tile[kq+3][nr])<<16);
    uint2 st; st.x = w0; st.y = w1;
    *(uint2*)&Wt[(size_t)(n0 + nr)*1024 + k0 + kq] = st;
  }
}

// =============================================================
// qm/km partials: k-split exact fp32 GEMM (round-5 proven version)
// =============================================================
__global__ __launch_bounds__(256) void qmkm_part(const float* __restrict__ xm,
    const float* __restrict__ Wq, const float* __restrict__ Wk,
    float* __restrict__ part){
  const int c  = blockIdx.x*256 + threadIdx.x;
  const int rg = blockIdx.y >> 3, ks = blockIdx.y & 7;
  const int z  = blockIdx.z;
  const float* W = z ? Wk : Wq;
  const int r0 = rg*16, k0 = ks*128;
  float acc[16];
#pragma unroll
  for (int r=0;r<16;++r) acc[r]=0.f;
  for (int k=0;k<128;k+=4){
    const float wv0 = W[(size_t)(k0+k  )*1024 + c];
    const float wv1 = W[(size_t)(k0+k+1)*1024 + c];
    const float wv2 = W[(size_t)(k0+k+2)*1024 + c];
    const float wv3 = W[(size_t)(k0+k+3)*1024 + c];
#pragma unroll
    for (int r=0;r<16;++r){
      const float4 xv = *(const float4*)&xm[(size_t)(r0+r)*1024 + k0 + k];
      acc[r] = fmaf(xv.w, wv3, fmaf(xv.z, wv2, fmaf(xv.y, wv1, fmaf(xv.x, wv0, acc[r]))));
    }
  }
  float* dst = part + (((size_t)z*8 + ks)*64 + r0)*1024 + c;
#pragma unroll
  for (int r=0;r<16;++r) dst[(size_t)r*1024] = acc[r];
}

__global__ __launch_bounds__(256) void qmkm_reduce(const float* __restrict__ part,
    const float* __restrict__ bq, const float* __restrict__ bk,
    float* __restrict__ qm, float* __restrict__ km){
  const int idx = blockIdx.x*256 + threadIdx.x;
  const int z = blockIdx.y;
  const int c = idx & 1023, r = idx >> 10;
  const float* p = part + ((size_t)z*8*64*1024) + (size_t)r*1024 + c;
  float s = 0.f;
#pragma unroll
  for (int ks=0; ks<8; ++ks) s += p[(size_t)ks*64*1024];
  s += z ? bk[c] : bq[c];
  (z ? km : qm)[(size_t)r*1024 + c] = s;
}

// =============================================================
// bf16 MFMA GEMM (QKV): 128x128, BK=32 TRIPLE-BUFFERED depth-2
// pipeline (vmcnt(8) steady state). 2-D XCD partition. SCALEQ folds
// attn's log2-domain Q prescale into the epilogue. (proven r12)
// =============================================================
#define G_STAGE(bsel, kofs) do { \
  gload16(A0 + (kofs), ldsA + (bsel)*4096 + (wid*2+0)*512); \
  gload16(A1 + (kofs), ldsA + (bsel)*4096 + (wid*2+1)*512); \
  gload16(B0 + (kofs), ldsB + (bsel)*4096 + (wid*2+0)*512); \
  gload16(B1 + (kofs), ldsB + (bsel)*4096 + (wid*2+1)*512); \
} while(0)

#define G_COMPUTE(bsel) do { \
  s16x8 af[4], bfr[4]; \
  _Pragma("unroll") \
  for (int mi=0;mi<4;++mi){ \
    int row = wr*64 + mi*16 + rl; \
    af[mi] = *(const s16x8*)((char*)ldsA + (bsel)*8192 + row*64 + ((g ^ ((row>>1)&3))<<4)); \
  } \
  _Pragma("unroll") \
  for (int ni=0;ni<4;++ni){ \
    int row = wc*64 + ni*16 + rl; \
    bfr[ni] = *(const s16x8*)((char*)ldsB + (bsel)*8192 + row*64 + ((g ^ ((row>>1)&3))<<4)); \
  } \
  _Pragma("unroll") \
  for (int mi=0;mi<4;++mi) \
    _Pragma("unroll") \
    for (int ni=0;ni<4;++ni) \
      acc[mi][ni] = __builtin_amdgcn_mfma_f32_16x16x32_bf16(af[mi], bfr[ni], acc[mi][ni], 0,0,0); \
} while(0)

template<int OUT_BF16, int SCALEQ>
__global__ __launch_bounds__(256) void gemm_bt(const unsigned short* __restrict__ A,
                                               const unsigned short* __restrict__ Bt,
                                               const float* __restrict__ bias,
                                               void* __restrict__ C, int N){
  constexpr int K = 1024;
  constexpr int NT = K/32;                          // 32 K-tiles
  __shared__ unsigned short ldsA[3*128*32];
  __shared__ unsigned short ldsB[3*128*32];
  const int t = threadIdx.x, lane = t & 63, wid = t >> 6;
  const int wr = wid >> 1, wc = wid & 1;
  const int rl = lane & 15, g = lane >> 4;

  const int nbx = gridDim.x, nby = gridDim.y;
  const int id  = blockIdx.y * nbx + blockIdx.x;
  const int xcd = id & 7, j = id >> 3;
  const int MBP = nby >> 2, NBP = nbx >> 1;
  const int mg = xcd >> 1, ng = xcd & 1;
  const int m0 = (mg*MBP + (j % MBP)) * 128;
  const int n0 = (ng*NBP + (j / MBP)) * 128;

  const f32x4 ZERO4 = {0.f,0.f,0.f,0.f};
  f32x4 acc[4][4];
#pragma unroll
  for (int i=0;i<4;++i)
#pragma unroll
    for (int j2=0;j2<4;++j2) acc[i][j2] = ZERO4;

  const int slot0 = wid*128 + lane, slot1 = slot0 + 64;
  const int sr0 = slot0>>2, sc0 = slot0&3;
  const int sr1 = slot1>>2, sc1 = slot1&3;
  const unsigned short* A0 = A  + (size_t)(m0 + sr0)*K + (sc0 ^ ((sr0>>1)&3))*8;
  const unsigned short* A1 = A  + (size_t)(m0 + sr1)*K + (sc1 ^ ((sr1>>1)&3))*8;
  const unsigned short* B0 = Bt + (size_t)(n0 + sr0)*K + (sc0 ^ ((sr0>>1)&3))*8;
  const unsigned short* B1 = Bt + (size_t)(n0 + sr1)*K + (sc1 ^ ((sr1>>1)&3))*8;

  G_STAGE(0, 0);
  G_STAGE(1, 32);

  for (int ti=0; ti<NT; ++ti){
    const int cur = ti % 3;
    if (ti+2 < NT){
      G_STAGE((ti+2)%3, (ti+2)*32);
      asm volatile("s_waitcnt vmcnt(8)" ::: "memory");
    } else if (ti+1 < NT){
      asm volatile("s_waitcnt vmcnt(4)" ::: "memory");
    } else {
      asm volatile("s_waitcnt vmcnt(0)" ::: "memory");
    }
    __builtin_amdgcn_s_barrier();
    __builtin_amdgcn_sched_barrier(0);
    G_COMPUTE(cur);
    __builtin_amdgcn_sched_barrier(0);
    __builtin_amdgcn_s_barrier();
  }

  const int r4 = g*4;
#pragma unroll
  for (int mi=0;mi<4;++mi){
#pragma unroll
    for (int ni=0;ni<4;++ni){
      int col = n0 + wc*64 + ni*16 + rl;
      float bb = bias[col];
      float sc = (SCALEQ && col < 1024) ? QSCALE : 1.0f;
#pragma unroll
      for (int e=0;e<4;++e){
        int row = m0 + wr*64 + mi*16 + r4 + e;
        float v = (acc[mi][ni][e] + bb) * sc;
        if (OUT_BF16) ((unsigned short*)C)[(size_t)row*N + col] = f2bf(v);
        else          ((float*)C)[(size_t)row*N + col] = v;
      }
    }
  }
}

// =============================================================
// O-proj GEMM: 128x64 tile, BK=32 triple-buffer counted-vmcnt
// pipeline (vmcnt(6) steady). (proven r15)
// =============================================================
#define G64_STAGE(bsel, kofs) do { \
  gload16(A0 + (kofs), ldsA + (bsel)*4096 + (wid*2+0)*512); \
  gload16(A1 + (kofs), ldsA + (bsel)*4096 + (wid*2+1)*512); \
  gload16(B0 + (kofs), ldsB + (bsel)*2048 + wid*512); \
} while(0)

#define G64_COMPUTE(bsel) do { \
  s16x8 af[4], bfr[2]; \
  _Pragma("unroll") \
  for (int mi=0;mi<4;++mi){ \
    int row = wr*64 + mi*16 + rl; \
    af[mi] = *(const s16x8*)((char*)ldsA + (bsel)*8192 + row*64 + ((g ^ ((row>>1)&3))<<4)); \
  } \
  _Pragma("unroll") \
  for (int ni=0;ni<2;++ni){ \
    int row = wc*32 + ni*16 + rl; \
    bfr[ni] = *(const s16x8*)((char*)ldsB + (bsel)*4096 + row*64 + ((g ^ ((row>>1)&3))<<4)); \
  } \
  _Pragma("unroll") \
  for (int mi=0;mi<4;++mi) \
    _Pragma("unroll") \
    for (int ni=0;ni<2;++ni) \
      acc[mi][ni] = __builtin_amdgcn_mfma_f32_16x16x32_bf16(af[mi], bfr[ni], acc[mi][ni], 0,0,0); \
} while(0)

__global__ __launch_bounds__(256) void gemm_bt64(const unsigned short* __restrict__ A,
                                                 const unsigned short* __restrict__ Bt,
                                                 const float* __restrict__ bias,
                                                 float* __restrict__ C, int N){
  constexpr int K = 1024;
  constexpr int NT = K/32;
  __shared__ unsigned short ldsA[3*128*32];
  __shared__ unsigned short ldsB[3*64*32];
  const int t = threadIdx.x, lane = t & 63, wid = t >> 6;
  const int wr = wid >> 1, wc = wid & 1;
  const int rl = lane & 15, g = lane >> 4;

  const int id  = blockIdx.y * gridDim.x + blockIdx.x;
  const int xcd = id & 7, j = id >> 3;            // j 0..63
  const int mg = xcd >> 1, ng = xcd & 1;
  const int m0 = (mg*8 + (j & 7)) * 128;          // 32 m-blocks
  const int n0 = (ng*8 + (j >> 3)) * 64;          // 16 n-blocks

  const f32x4 ZERO4 = {0.f,0.f,0.f,0.f};
  f32x4 acc[4][2];
#pragma unroll
  for (int i=0;i<4;++i)
#pragma unroll
    for (int j2=0;j2<2;++j2) acc[i][j2] = ZERO4;

  const int slot0 = wid*128 + lane, slot1 = slot0 + 64;
  const int sr0 = slot0>>2, sc0 = slot0&3;
  const int sr1 = slot1>>2, sc1 = slot1&3;
  const unsigned short* A0 = A + (size_t)(m0 + sr0)*K + (sc0 ^ ((sr0>>1)&3))*8;
  const unsigned short* A1 = A + (size_t)(m0 + sr1)*K + (sc1 ^ ((sr1>>1)&3))*8;
  const int slotB = wid*64 + lane;
  const int srB = slotB>>2, scB = slotB&3;
  const unsigned short* B0 = Bt + (size_t)(n0 + srB)*K + (scB ^ ((srB>>1)&3))*8;

  G64_STAGE(0, 0);
  G64_STAGE(1, 32);

  for (int ti=0; ti<NT; ++ti){
    const int cur = ti % 3;
    if (ti+2 < NT){
      G64_STAGE((ti+2)%3, (ti+2)*32);
      asm volatile("s_waitcnt vmcnt(6)" ::: "memory");
    } else if (ti+1 < NT){
      asm volatile("s_waitcnt vmcnt(3)" ::: "memory");
    } else {
      asm volatile("s_waitcnt vmcnt(0)" ::: "memory");
    }
    __builtin_amdgcn_s_barrier();
    __builtin_amdgcn_sched_barrier(0);
    G64_COMPUTE(cur);
    __builtin_amdgcn_sched_barrier(0);
    __builtin_amdgcn_s_barrier();
  }

  const int r4 = g*4;
#pragma unroll
  for (int mi=0;mi<4;++mi){
#pragma unroll
    for (int ni=0;ni<2;++ni){
      int col = n0 + wc*32 + ni*16 + rl;
      float bb = bias[col];
#pragma unroll
      for (int e=0;e<4;++e){
        int row = m0 + wr*64 + mi*16 + r4 + e;
        C[(size_t)row*N + col] = acc[mi][ni][e] + bb;
      }
    }
  }
}

// =============================================================
// Sparse flash attention v9: proven v6 body + INLINE top-16
// selection (exact fp32 topk replicated per block — removes the
// separate topk launch and the sel round-trip). PAIRED balanced
// blocks + XCD pinning; fixed-max log2 softmax; cvtpk+bpermute PV.
// =============================================================
__global__ __launch_bounds__(256) void attn_kernel(const unsigned short* __restrict__ qkv,
                                                   const float* __restrict__ qm,
                                                   const float* __restrict__ km,
                                                   unsigned short* __restrict__ ctx){
  const int id = blockIdx.x;                 // 0..767
  const int xcd = id & 7, jj = id >> 3;      // jj 0..95
  const int bh = xcd + 8*(jj/24);
  const int tau = jj % 24;
  const int h = bh & 15, b = bh >> 4;
  int qbl[2]; int nq;
  if (tau < 8){ qbl[0]=tau; qbl[1]=15-tau; nq=2; }
  else        { qbl[0]=tau+8; qbl[1]=0;    nq=1; }

  const int t = threadIdx.x, wid = t >> 6, lane = t & 63;
  const int rl = lane & 15, g = lane >> 4;
  const int q_local = wid*16 + rl;

  __shared__ unsigned short K_s[2][4096];    // [j 64][128B], chunk^(j&7) swizzle
  __shared__ unsigned short V_s[2][4096];    // V^T [d 64][128B], chunk^((d&7)^(d>>3))
  __shared__ float sim[32];
  __shared__ int keep[32];
  __shared__ int sel_l[19];                  // [0]=count, [1..] block ids

  const int jst = t >> 2, cq = t & 3;        // K: row jst, chunks 2cq, 2cq+1
  const int r2 = t >> 3, dq = t & 7;         // V: rows 2r2,2r2+1, d-base dq*8
  const unsigned short* kbase = qkv + (size_t)(b*Sdim + jst)*3072 + 1024 + h*DH + cq*16;
  const unsigned short* vbase = qkv + (size_t)(b*Sdim + 2*r2)*3072 + 2048 + h*DH + dq*8;
  const int kwb0 = jst*128 + (((cq*2  ) ^ (jst&7))<<4);
  const int kwb1 = jst*128 + (((cq*2+1) ^ (jst&7))<<4);
  const f32x4 ZERO4 = {0.f,0.f,0.f,0.f};

  const int src0 = (rl + 16*((2*g  ) & 3)) << 2;
  const int src1 = (rl + 16*((2*g+1) & 3)) << 2;
  const bool hsel = (g >> 1);

  for (int iq=0; iq<nq; ++iq){
    const int qb = qbl[iq];

    // ---- inline top-16 selection (exact fp32, same as reference) ----
    __syncthreads();            // prev-qb readers done; sim/sel_l free
    {
      const int kb2 = t>>3, l8 = t&7;
      float acc2 = 0.f;
      if (kb2 <= qb){
        const float* qv = qm + (size_t)(b*32 + qb)*1024 + h*64;
        const float* kv = km + (size_t)(b*32 + kb2)*1024 + h*64;
#pragma unroll
        for (int d=0; d<8; ++d) acc2 += qv[l8*8+d] * kv[l8*8+d];
      }
      acc2 += __shfl_xor(acc2,1); acc2 += __shfl_xor(acc2,2); acc2 += __shfl_xor(acc2,4);
      if (l8==0) sim[kb2] = (kb2<=qb) ? acc2 : -1e30f;
      __syncthreads();
      if (t < 32){
        int k2 = t; int ok = 0;
        if (k2 <= qb){
          float sv = sim[k2]; int rank = 0;
          for (int j2=0;j2<=qb;++j2){
            float sj = sim[j2];
            rank += (sj > sv) || (sj == sv && j2 < k2);
          }
          ok = (rank < 16) || (k2 == qb);
        }
        keep[t] = ok;
      }
      __syncthreads();
      if (t == 0){
        int c = 0;
        for (int j2=0;j2<32;++j2) if (keep[j2]) sel_l[1+c++] = j2;
        sel_l[0] = c;
      }
      __syncthreads();
    }
    const int ns = sel_l[0];

    const int qg0 = b*Sdim + qb*64 + q_local;
    const unsigned short* qbase = qkv + (size_t)qg0*3072 + h*DH;
    s16x8 qa[2];                 // raw loads — prescale done in GEMM epilogue
    qa[0] = *(const s16x8*)(qbase + g*8);
    qa[1] = *(const s16x8*)(qbase + 32 + g*8);

    f32x4 o[4];                  // O^T: o[f][e] = O[q=q_local][d = f*16 + g*4 + e]
    float l_p = 0.f;             // per-lane partial denominator
#pragma unroll
    for (int f=0; f<4; ++f) o[f] = ZERO4;

    int kb = sel_l[1];
    s16x8 kr0, kr1, vr0, vr1;
    {
      const size_t off = (size_t)kb*64*3072;
      kr0 = *(const s16x8*)(kbase + off);
      kr1 = *(const s16x8*)(kbase + off + 8);
      vr0 = *(const s16x8*)(vbase + off);
      vr1 = *(const s16x8*)(vbase + off + 3072);
    }

    for (int it=0; it<ns; ++it){
      const int buf = it & 1;
      unsigned short* Kw = &K_s[buf][0];
      unsigned short* Vw = &V_s[buf][0];
      *(s16x8*)((char*)Kw + kwb0) = kr0;
      *(s16x8*)((char*)Kw + kwb1) = kr1;
#pragma unroll
      for (int e=0;e<8;++e){
        const int d1 = dq*8 + e;
        const int sw = (d1&7) ^ (d1>>3);
        const unsigned int pr = (unsigned int)(unsigned short)vr0[e]
                              | ((unsigned int)(unsigned short)vr1[e] << 16);
        *(unsigned int*)((char*)Vw + d1*128 + ((4*r2) ^ (sw<<4))) = pr;
      }
      const int kbcur = kb;
      if (it+1 < ns){
        kb = sel_l[2+it];
        const size_t off = (size_t)kb*64*3072;
        kr0 = *(const s16x8*)(kbase + off);
        kr1 = *(const s16x8*)(kbase + off + 8);
        vr0 = *(const s16x8*)(vbase + off);
        vr1 = *(const s16x8*)(vbase + off + 3072);
      }
      __syncthreads();

      // ---- S^T = K Q'^T  (log2 domain via Q prescale) ----
      f32x4 sfT[4];
#pragma unroll
      for (int f=0;f<4;++f) sfT[f] = ZERO4;
      __builtin_amdgcn_s_setprio(1);
#pragma unroll
      for (int kk=0;kk<2;++kk){
#pragma unroll
        for (int f=0;f<4;++f){
          const int jr = f*16 + rl;
          s16x8 kf = *(const s16x8*)((char*)Kw + jr*128 + (((kk*4+g) ^ (jr&7))<<4));
          sfT[f] = __builtin_amdgcn_mfma_f32_16x16x32_bf16(kf, qa[kk], sfT[f], 0,0,0);
        }
      }
      __builtin_amdgcn_s_setprio(0);
      if (kbcur == qb){
#pragma unroll
        for (int f=0;f<4;++f)
#pragma unroll
          for (int e=0;e<4;++e){
            const int j2 = f*16 + g*4 + e;
            if (j2 > q_local) sfT[f][e] = -1e9f;
          }
      }
      // ---- fixed-max softmax weights: p = 2^(S - MFIX) ----
      {
        float rs = 0.f;
#pragma unroll
        for (int f=0;f<4;++f)
#pragma unroll
          for (int e=0;e<4;++e){
            const float p = exp2fast(sfT[f][e] - MFIX);
            sfT[f][e] = p; rs += p;
          }
        l_p += rs;
      }

      unsigned int plo[4], phi[4];
#pragma unroll
      for (int f=0;f<4;++f){
        plo[f] = cvtpk(sfT[f][0], sfT[f][1]);
        phi[f] = cvtpk(sfT[f][2], sfT[f][3]);
      }

#pragma unroll
      for (int kk=0;kk<2;++kk){
        const int f0 = 2*kk, f1 = 2*kk+1;
        unsigned int a0, b0, w0, w1, w2, w3;
        a0 = __builtin_amdgcn_ds_bpermute(src0, plo[f0]);
        b0 = __builtin_amdgcn_ds_bpermute(src0, plo[f1]);
        w0 = hsel ? b0 : a0;
        a0 = __builtin_amdgcn_ds_bpermute(src0, phi[f0]);
        b0 = __builtin_amdgcn_ds_bpermute(src0, phi[f1]);
        w1 = hsel ? b0 : a0;
        a0 = __builtin_amdgcn_ds_bpermute(src1, plo[f0]);
        b0 = __builtin_amdgcn_ds_bpermute(src1, plo[f1]);
        w2 = hsel ? b0 : a0;
        a0 = __builtin_amdgcn_ds_bpermute(src1, phi[f0]);
        b0 = __builtin_amdgcn_ds_bpermute(src1, phi[f1]);
        w3 = hsel ? b0 : a0;
        union { unsigned int u[4]; s16x8 v; } pfc;
        pfc.u[0] = w0; pfc.u[1] = w1; pfc.u[2] = w2; pfc.u[3] = w3;
        const s16x8 pf = pfc.v;
        __builtin_amdgcn_s_setprio(1);
#pragma unroll
        for (int f=0;f<4;++f){
          const int d = f*16 + rl;
          const int sw = (d&7) ^ (d>>3);
          s16x8 vf = *(const s16x8*)((char*)Vw + d*128 + ((64*kk + 16*g) ^ (sw<<4)));
          o[f] = __builtin_amdgcn_mfma_f32_16x16x32_bf16(vf, pf, o[f], 0,0,0);
        }
        __builtin_amdgcn_s_setprio(0);
      }
    }

    {
      float l_r = l_p;
      l_r += __shfl_xor(l_r, 16);
      l_r += __shfl_xor(l_r, 32);
      const float inv = 1.f / l_r;
      unsigned short* crow = ctx + (size_t)qg0*Ddim + h*DH;
#pragma unroll
      for (int f=0;f<4;++f){
        uint2 st;
        st.x = (unsigned int)f2bf(o[f][0]*inv) | ((unsigned int)f2bf(o[f][1]*inv)<<16);
        st.y = (unsigned int)f2bf(o[f][2]*inv) | ((unsigned int)f2bf(o[f][3]*inv)<<16);
        *(uint2*)(crow + f*16 + g*4) = st;
      }
    }
  }
}

// =============================================================
extern "C" void kernel_launch(void* const* d_in, const int* in_sizes, int n_in,
                              void* d_out, int out_size, void* d_ws, size_t ws_size,
                              hipStream_t stream){
  (void)in_sizes; (void)n_in; (void)out_size; (void)ws_size;
  const float* inp  = (const float*)d_in[0];
  const float* ln_g = (const float*)d_in[1];
  const float* ln_b = (const float*)d_in[2];
  const float* Wq   = (const float*)d_in[3];
  const float* bq   = (const float*)d_in[4];
  const float* Wk   = (const float*)d_in[5];
  const float* bk   = (const float*)d_in[6];
  const float* Wv   = (const float*)d_in[7];
  const float* bv   = (const float*)d_in[8];
  const float* Wo   = (const float*)d_in[9];
  const float* bo   = (const float*)d_in[10];

  char* ws = (char*)d_ws;
  unsigned short* xb    = (unsigned short*)(ws + OFF_XB);
  unsigned short* wtqkv = (unsigned short*)(ws + OFF_WTQKV);
  unsigned short* wot   = (unsigned short*)(ws + OFF_WOT);
  unsigned short* qkvb  = (unsigned short*)(ws + OFF_QKV);
  unsigned short* ctx   = (unsigned short*)(ws + OFF_CTX);
  float* xm   = (float*)(ws + OFF_XM);
  float* qm   = (float*)(ws + OFF_QM);
  float* km   = (float*)(ws + OFF_KM);
  float* bqkv = (float*)(ws + OFF_BIASQ);
  float* part = (float*)(ws + OFF_PART);

  prep_kernel<<<8256, 256, 0, stream>>>(inp, ln_g, ln_b, Wq, Wk, Wv, Wo,
                                        bq, bk, bv, xb, xm, wtqkv, wot, bqkv);
  qmkm_part<<<dim3(4,32,2), 256, 0, stream>>>(xm, Wq, Wk, part);
  qmkm_reduce<<<dim3(256,2), 256, 0, stream>>>(part, bq, bk, qm, km);
  gemm_bt<1,1><<<dim3(24,32), 256, 0, stream>>>(xb, wtqkv, bqkv, (void*)qkvb, 3072);
  attn_kernel<<<768, 256, 0, stream>>>(qkvb, qm, km, ctx);
  gemm_bt64<<<dim3(16,32), 256, 0, stream>>>(ctx, wot, bo, (float*)d_out, 1024);
}

// Round 19
// 134.440 us; speedup vs baseline: 1.0509x; 1.0020x over previous
//
#include <hip/hip_runtime.h>
#include <stdint.h>

#define DEV static __device__ __forceinline__

typedef __attribute__((ext_vector_type(8))) short s16x8;   // 8 bf16 in 4 VGPRs
typedef __attribute__((ext_vector_type(4))) float f32x4;   // MFMA acc

// ---------- problem constants ----------
constexpr int Bdim = 2, Sdim = 2048, Ddim = 1024, Hdim = 16, DH = 64;
constexpr int Mrows = Bdim * Sdim;      // 4096
constexpr int NB = 32;                  // S / 64
constexpr int SEL_STRIDE = 18;          // [count, up to 17 block ids]

// Q prescale folded into QKV epilogue: 1/sqrt(64) * log2(e)
#define QSCALE 0.18033688011112042f
#define MFIX   8.0f                     // fixed softmax max (log2 domain, >=5 sigma margin)

// ---------- workspace layout (bytes) ----------
constexpr size_t OFF_XB    = 0;                                        // x bf16 [4096][1024]
constexpr size_t OFF_WTQKV = OFF_XB    + (size_t)Mrows*Ddim*2;         // Wqkv^T bf16 [3072][1024]
constexpr size_t OFF_WOT   = OFF_WTQKV + (size_t)3072*1024*2;          // Wo^T bf16 [1024][1024]
constexpr size_t OFF_QKV   = OFF_WOT   + (size_t)1024*1024*2;          // qkv bf16 [4096][3072]
constexpr size_t OFF_CTX   = OFF_QKV   + (size_t)Mrows*3072*2;         // ctx bf16 [4096][1024]
constexpr size_t OFF_XM    = OFF_CTX   + (size_t)Mrows*Ddim*2;         // xm f32 [64][1024]
constexpr size_t OFF_QM    = OFF_XM    + (size_t)64*1024*4;            // qm f32 [64][1024]
constexpr size_t OFF_KM    = OFF_QM    + (size_t)64*1024*4;            // km f32 [64][1024]
constexpr size_t OFF_BIASQ = OFF_KM    + (size_t)64*1024*4;            // f32 [3072]
constexpr size_t OFF_SEL   = OFF_BIASQ + (size_t)3072*4;               // int [1024][18]
constexpr size_t OFF_PART  = OFF_SEL   + (size_t)1024*SEL_STRIDE*4;    // f32 [2][8][64][1024]

DEV float bf2f(unsigned short u){ union{unsigned int i; float f;} x; x.i = ((unsigned int)u)<<16; return x.f; }
DEV unsigned short f2bf(float f){ union{float f; unsigned int i;} x; x.f=f;
  unsigned int r = x.i + 0x7fffu + ((x.i>>16)&1u); return (unsigned short)(r>>16); }

// global -> LDS async 16B (per-wave: lane l writes ldsbase + l*16)
DEV void gload16(const unsigned short* g, unsigned short* l){
  __builtin_amdgcn_global_load_lds(
      (__attribute__((address_space(1))) void*)(void*)g,
      (__attribute__((address_space(3))) void*)l, 16, 0, 0);
}

DEV unsigned int cvtpk(float a, float b){
  unsigned int r;
  asm("v_cvt_pk_bf16_f32 %0, %1, %2" : "=v"(r) : "v"(a), "v"(b));
  return r;
}

DEV float exp2fast(float x){           // D = 2^x (v_exp_f32 is natively base-2)
  float r;
  asm("v_exp_f32 %0, %1" : "=v"(r) : "v"(x));
  return r;
}

// =============================================================
// prep: fused {ln (blocks 0..4095), xm (4096..4159),
//              wtrans4+biascat (4160..8255)} — all input-only.
// =============================================================
__global__ __launch_bounds__(256) void prep_kernel(const float* __restrict__ inp,
                                                   const float* __restrict__ gam,
                                                   const float* __restrict__ bet,
                                                   const float* __restrict__ Wq,
                                                   const float* __restrict__ Wk,
                                                   const float* __restrict__ Wv,
                                                   const float* __restrict__ Wo,
                                                   const float* __restrict__ bq,
                                                   const float* __restrict__ bk,
                                                   const float* __restrict__ bv,
                                                   unsigned short* __restrict__ xb,
                                                   float* __restrict__ xm,
                                                   unsigned short* __restrict__ wtqkv,
                                                   unsigned short* __restrict__ wot,
                                                   float* __restrict__ bqkv){
  __shared__ float sh[4][1024];          // 16KB union for all three roles
  const int bid = blockIdx.x;
  const int t = threadIdx.x;

  if (bid < 4096){
    // ---------------- ln: one row ----------------
    const int row = bid;
    float* red = &sh[0][0];
    const float4 v = ((const float4*)(inp + (size_t)row*Ddim))[t];
    float s  = v.x + v.y + v.z + v.w;
    float s2 = v.x*v.x + v.y*v.y + v.z*v.z + v.w*v.w;
#pragma unroll
    for (int mk=32; mk>=1; mk>>=1){ s += __shfl_xor(s, mk); s2 += __shfl_xor(s2, mk); }
    if ((t&63)==0){ red[t>>6] = s; red[4+(t>>6)] = s2; }
    __syncthreads();
    s  = red[0]+red[1]+red[2]+red[3];
    s2 = red[4]+red[5]+red[6]+red[7];
    const float mu  = s * (1.f/Ddim);
    const float var = s2 * (1.f/Ddim) - mu*mu;
    const float rs  = rsqrtf(var + 1e-5f);
    const float4 gv = ((const float4*)gam)[t];
    const float4 bv2 = ((const float4*)bet)[t];
    float o0 = (v.x-mu)*rs*gv.x + bv2.x;
    float o1 = (v.y-mu)*rs*gv.y + bv2.y;
    float o2 = (v.z-mu)*rs*gv.z + bv2.z;
    float o3 = (v.w-mu)*rs*gv.w + bv2.w;
    uint2 u;
    u.x = (unsigned int)f2bf(o0) | ((unsigned int)f2bf(o1)<<16);
    u.y = (unsigned int)f2bf(o2) | ((unsigned int)f2bf(o3)<<16);
    ((uint2*)(xb + (size_t)row*Ddim))[t] = u;
  } else if (bid < 4160){
    // ---------------- xm: one 64-row block ----------------
    const int blk = bid - 4096;
    const int w = t>>6, lane = t&63;
    float4 gv[4], bvv[4];
#pragma unroll
    for (int p=0;p<4;++p){ gv[p] = ((const float4*)gam)[lane + 64*p];
                           bvv[p] = ((const float4*)bet)[lane + 64*p]; }
    float ax[4][4];
#pragma unroll
    for (int p=0;p<4;++p)
#pragma unroll
      for (int c=0;c<4;++c) ax[p][c]=0.f;
    for (int rr=0; rr<16; ++rr){
      const int row = blk*64 + w*16 + rr;
      const float4* rp = (const float4*)(inp + (size_t)row*Ddim);
      float4 v[4]; float s=0.f, s2=0.f;
#pragma unroll
      for (int p=0;p<4;++p){
        v[p] = rp[lane + 64*p];
        s  += v[p].x+v[p].y+v[p].z+v[p].w;
        s2 += v[p].x*v[p].x+v[p].y*v[p].y+v[p].z*v[p].z+v[p].w*v[p].w;
      }
#pragma unroll
      for (int mk=32; mk>=1; mk>>=1){ s += __shfl_xor(s,mk); s2 += __shfl_xor(s2,mk); }
      const float mu = s*(1.f/Ddim);
      const float var = s2*(1.f/Ddim) - mu*mu;
      const float rs = rsqrtf(var + 1e-5f);
#pragma unroll
      for (int p=0;p<4;++p){
        ax[p][0] += (v[p].x-mu)*rs*gv[p].x + bvv[p].x;
        ax[p][1] += (v[p].y-mu)*rs*gv[p].y + bvv[p].y;
        ax[p][2] += (v[p].z-mu)*rs*gv[p].z + bvv[p].z;
        ax[p][3] += (v[p].w-mu)*rs*gv[p].w + bvv[p].w;
      }
    }
#pragma unroll
    for (int p=0;p<4;++p){
      float4 o; o.x=ax[p][0]; o.y=ax[p][1]; o.z=ax[p][2]; o.w=ax[p][3];
      ((float4*)&sh[w][0])[lane + 64*p] = o;
    }
    __syncthreads();
    float4 r0 = ((float4*)&sh[0][0])[t];
    float4 r1 = ((float4*)&sh[1][0])[t];
    float4 r2 = ((float4*)&sh[2][0])[t];
    float4 r3 = ((float4*)&sh[3][0])[t];
    float4 o;
    o.x = (r0.x+r1.x+r2.x+r3.x)*(1.f/64);
    o.y = (r0.y+r1.y+r2.y+r3.y)*(1.f/64);
    o.z = (r0.z+r1.z+r2.z+r3.z)*(1.f/64);
    o.w = (r0.w+r1.w+r2.w+r3.w)*(1.f/64);
    ((float4*)(xm + (size_t)blk*Ddim))[t] = o;
  } else {
    // ---------------- wtrans: one 32x32 tile ----------------
    const int wt = bid - 4160;
    const int z = wt >> 10, rem = wt & 1023;
    const int bx = rem & 31, by = rem >> 5;
    const float* W = (z==0)?Wq:(z==1)?Wk:(z==2)?Wv:Wo;
    unsigned short* Wt = (z<3) ? (wtqkv + (size_t)z*1024*1024) : wot;
    const int n0 = bx*32, k0 = by*32;
    const int r = t>>5, c = t&31;
    float (*tile)[33] = (float(*)[33])&sh[0][0];
    if (z<3 && bx==0 && by==0){
      const float* bb = (z==0)?bq:(z==1)?bk:bv;
#pragma unroll
      for (int i=0;i<4;++i) bqkv[z*1024 + t + 256*i] = bb[t + 256*i];
    }
#pragma unroll
    for (int i=0;i<4;++i) tile[r+8*i][c] = W[(size_t)(k0 + r + 8*i)*1024 + n0 + c];
    __syncthreads();
    const int nr = t >> 3, kq = (t & 7) * 4;
    unsigned int w0 = (unsigned int)f2bf(tile[kq  ][nr]) | ((unsigned int)f2bf(tile[kq+1][nr])<<16);
    unsigned int w1 = (unsigned int)f2bf(tile[kq+2][nr]) | ((unsigned int)f2bf(tile[kq+3][nr])<<16);
    uint2 st; st.x = w0; st.y = w1;
    *(uint2*)&Wt[(size_t)(n0 + nr)*1024 + k0 + kq] = st;
  }
}

// =============================================================
// qm/km partials: k-split exact fp32 GEMM (round-5 proven version)
// =============================================================
__global__ __launch_bounds__(256) void qmkm_part(const float* __restrict__ xm,
    const float* __restrict__ Wq, const float* __restrict__ Wk,
    float* __restrict__ part){
  const int c  = blockIdx.x*256 + threadIdx.x;
  const int rg = blockIdx.y >> 3, ks = blockIdx.y & 7;
  const int z  = blockIdx.z;
  const float* W = z ? Wk : Wq;
  const int r0 = rg*16, k0 = ks*128;
  float acc[16];
#pragma unroll
  for (int r=0;r<16;++r) acc[r]=0.f;
  for (int k=0;k<128;k+=4){
    const float wv0 = W[(size_t)(k0+k  )*1024 + c];
    const float wv1 = W[(size_t)(k0+k+1)*1024 + c];
    const float wv2 = W[(size_t)(k0+k+2)*1024 + c];
    const float wv3 = W[(size_t)(k0+k+3)*1024 + c];
#pragma unroll
    for (int r=0;r<16;++r){
      const float4 xv = *(const float4*)&xm[(size_t)(r0+r)*1024 + k0 + k];
      acc[r] = fmaf(xv.w, wv3, fmaf(xv.z, wv2, fmaf(xv.y, wv1, fmaf(xv.x, wv0, acc[r]))));
    }
  }
  float* dst = part + (((size_t)z*8 + ks)*64 + r0)*1024 + c;
#pragma unroll
  for (int r=0;r<16;++r) dst[(size_t)r*1024] = acc[r];
}

__global__ __launch_bounds__(256) void qmkm_reduce(const float* __restrict__ part,
    const float* __restrict__ bq, const float* __restrict__ bk,
    float* __restrict__ qm, float* __restrict__ km){
  const int idx = blockIdx.x*256 + threadIdx.x;
  const int z = blockIdx.y;
  const int c = idx & 1023, r = idx >> 10;
  const float* p = part + ((size_t)z*8*64*1024) + (size_t)r*1024 + c;
  float s = 0.f;
#pragma unroll
  for (int ks=0; ks<8; ++ks) s += p[(size_t)ks*64*1024];
  s += z ? bk[c] : bq[c];
  (z ? km : qm)[(size_t)r*1024 + c] = s;
}

// =============================================================
// QKV GEMM + TOPK fused launch: blocks 0..767 run the proven
// 128x128 BK=32 triple-buffered depth-2 GEMM (2-D XCD partition,
// Q-prescale epilogue); blocks 768..1791 run the proven fp32 top-16
// selection (qm/km ready before this launch). Separate code paths,
// GEMM regalloc dominates (topk branch is light).
// =============================================================
#define G_STAGE(bsel, kofs) do { \
  gload16(A0 + (kofs), ldsA + (bsel)*4096 + (wid*2+0)*512); \
  gload16(A1 + (kofs), ldsA + (bsel)*4096 + (wid*2+1)*512); \
  gload16(B0 + (kofs), ldsB + (bsel)*4096 + (wid*2+0)*512); \
  gload16(B1 + (kofs), ldsB + (bsel)*4096 + (wid*2+1)*512); \
} while(0)

#define G_COMPUTE(bsel) do { \
  s16x8 af[4], bfr[4]; \
  _Pragma("unroll") \
  for (int mi=0;mi<4;++mi){ \
    int row = wr*64 + mi*16 + rl; \
    af[mi] = *(const s16x8*)((char*)ldsA + (bsel)*8192 + row*64 + ((g ^ ((row>>1)&3))<<4)); \
  } \
  _Pragma("unroll") \
  for (int ni=0;ni<4;++ni){ \
    int row = wc*64 + ni*16 + rl; \
    bfr[ni] = *(const s16x8*)((char*)ldsB + (bsel)*8192 + row*64 + ((g ^ ((row>>1)&3))<<4)); \
  } \
  _Pragma("unroll") \
  for (int mi=0;mi<4;++mi) \
    _Pragma("unroll") \
    for (int ni=0;ni<4;++ni) \
      acc[mi][ni] = __builtin_amdgcn_mfma_f32_16x16x32_bf16(af[mi], bfr[ni], acc[mi][ni], 0,0,0); \
} while(0)

__global__ __launch_bounds__(256) void gemm_qkv_topk(const unsigned short* __restrict__ A,
                                                     const unsigned short* __restrict__ Bt,
                                                     const float* __restrict__ bias,
                                                     unsigned short* __restrict__ C,
                                                     const float* __restrict__ qm,
                                                     const float* __restrict__ km,
                                                     int* __restrict__ sel){
  constexpr int K = 1024;
  constexpr int NT = K/32;                          // 32 K-tiles
  constexpr int N = 3072;
  __shared__ unsigned short ldsA[3*128*32];
  __shared__ unsigned short ldsB[3*128*32];
  const int t = threadIdx.x;

  if (blockIdx.x >= 768){
    // ---------------- topk branch (proven fp32 selection) ----------------
    float* sim = (float*)&ldsA[0];
    int*   keep = (int*)&ldsA[64];
    const int bhq = blockIdx.x - 768;
    const int qb = bhq & 31, h = (bhq>>5) & 15, b = bhq >> 9;
    const int kb = t>>3, l8 = t&7;
    float acc2 = 0.f;
    if (kb <= qb){
      const float* qv = qm + (size_t)(b*32 + qb)*1024 + h*64;
      const float* kv = km + (size_t)(b*32 + kb)*1024 + h*64;
#pragma unroll
      for (int d=0; d<8; ++d) acc2 += qv[l8*8+d] * kv[l8*8+d];
    }
    acc2 += __shfl_xor(acc2,1); acc2 += __shfl_xor(acc2,2); acc2 += __shfl_xor(acc2,4);
    if (l8==0) sim[kb] = (kb<=qb) ? acc2 : -1e30f;
    __syncthreads();
    if (t < 32){
      int k2 = t; int ok = 0;
      if (k2 <= qb){
        float sv = sim[k2]; int rank = 0;
        for (int j2=0;j2<=qb;++j2){
          float sj = sim[j2];
          rank += (sj > sv) || (sj == sv && j2 < k2);
        }
        ok = (rank < 16) || (k2 == qb);
      }
      keep[t] = ok;
    }
    __syncthreads();
    if (t == 0){
      int* dstp = sel + (size_t)bhq * SEL_STRIDE;
      int c = 0;
      for (int j2=0;j2<32;++j2) if (keep[j2]) dstp[1+c++] = j2;
      dstp[0] = c;
    }
    return;
  }

  // ---------------- GEMM branch (proven r12 structure) ----------------
  const int lane = t & 63, wid = t >> 6;
  const int wr = wid >> 1, wc = wid & 1;
  const int rl = lane & 15, g = lane >> 4;

  constexpr int nbx = 24, nby = 32;
  const int id  = blockIdx.x;                       // linear == old by*24+bx
  const int xcd = id & 7, j = id >> 3;
  const int MBP = nby >> 2, NBP = nbx >> 1;
  const int mg = xcd >> 1, ng = xcd & 1;
  const int m0 = (mg*MBP + (j % MBP)) * 128;
  const int n0 = (ng*NBP + (j / MBP)) * 128;

  const f32x4 ZERO4 = {0.f,0.f,0.f,0.f};
  f32x4 acc[4][4];
#pragma unroll
  for (int i=0;i<4;++i)
#pragma unroll
    for (int j2=0;j2<4;++j2) acc[i][j2] = ZERO4;

  const int slot0 = wid*128 + lane, slot1 = slot0 + 64;
  const int sr0 = slot0>>2, sc0 = slot0&3;
  const int sr1 = slot1>>2, sc1 = slot1&3;
  const unsigned short* A0 = A  + (size_t)(m0 + sr0)*K + (sc0 ^ ((sr0>>1)&3))*8;
  const unsigned short* A1 = A  + (size_t)(m0 + sr1)*K + (sc1 ^ ((sr1>>1)&3))*8;
  const unsigned short* B0 = Bt + (size_t)(n0 + sr0)*K + (sc0 ^ ((sr0>>1)&3))*8;
  const unsigned short* B1 = Bt + (size_t)(n0 + sr1)*K + (sc1 ^ ((sr1>>1)&3))*8;

  G_STAGE(0, 0);
  G_STAGE(1, 32);

  for (int ti=0; ti<NT; ++ti){
    const int cur = ti % 3;
    if (ti+2 < NT){
      G_STAGE((ti+2)%3, (ti+2)*32);
      asm volatile("s_waitcnt vmcnt(8)" ::: "memory");
    } else if (ti+1 < NT){
      asm volatile("s_waitcnt vmcnt(4)" ::: "memory");
    } else {
      asm volatile("s_waitcnt vmcnt(0)" ::: "memory");
    }
    __builtin_amdgcn_s_barrier();
    __builtin_amdgcn_sched_barrier(0);
    G_COMPUTE(cur);
    __builtin_amdgcn_sched_barrier(0);
    __builtin_amdgcn_s_barrier();
  }

  const int r4 = g*4;
#pragma unroll
  for (int mi=0;mi<4;++mi){
#pragma unroll
    for (int ni=0;ni<4;++ni){
      int col = n0 + wc*64 + ni*16 + rl;
      float bb = bias[col];
      float sc = (col < 1024) ? QSCALE : 1.0f;
#pragma unroll
      for (int e=0;e<4;++e){
        int row = m0 + wr*64 + mi*16 + r4 + e;
        float v = (acc[mi][ni][e] + bb) * sc;
        C[(size_t)row*N + col] = f2bf(v);
      }
    }
  }
}

// =============================================================
// O-proj GEMM: 128x64 tile, BK=32 triple-buffer counted-vmcnt
// pipeline (vmcnt(6) steady). (proven r15)
// =============================================================
#define G64_STAGE(bsel, kofs) do { \
  gload16(A0 + (kofs), ldsA + (bsel)*4096 + (wid*2+0)*512); \
  gload16(A1 + (kofs), ldsA + (bsel)*4096 + (wid*2+1)*512); \
  gload16(B0 + (kofs), ldsB + (bsel)*2048 + wid*512); \
} while(0)

#define G64_COMPUTE(bsel) do { \
  s16x8 af[4], bfr[2]; \
  _Pragma("unroll") \
  for (int mi=0;mi<4;++mi){ \
    int row = wr*64 + mi*16 + rl; \
    af[mi] = *(const s16x8*)((char*)ldsA + (bsel)*8192 + row*64 + ((g ^ ((row>>1)&3))<<4)); \
  } \
  _Pragma("unroll") \
  for (int ni=0;ni<2;++ni){ \
    int row = wc*32 + ni*16 + rl; \
    bfr[ni] = *(const s16x8*)((char*)ldsB + (bsel)*4096 + row*64 + ((g ^ ((row>>1)&3))<<4)); \
  } \
  _Pragma("unroll") \
  for (int mi=0;mi<4;++mi) \
    _Pragma("unroll") \
    for (int ni=0;ni<2;++ni) \
      acc[mi][ni] = __builtin_amdgcn_mfma_f32_16x16x32_bf16(af[mi], bfr[ni], acc[mi][ni], 0,0,0); \
} while(0)

__global__ __launch_bounds__(256) void gemm_bt64(const unsigned short* __restrict__ A,
                                                 const unsigned short* __restrict__ Bt,
                                                 const float* __restrict__ bias,
                                                 float* __restrict__ C, int N){
  constexpr int K = 1024;
  constexpr int NT = K/32;
  __shared__ unsigned short ldsA[3*128*32];
  __shared__ unsigned short ldsB[3*64*32];
  const int t = threadIdx.x, lane = t & 63, wid = t >> 6;
  const int wr = wid >> 1, wc = wid & 1;
  const int rl = lane & 15, g = lane >> 4;

  const int id  = blockIdx.y * gridDim.x + blockIdx.x;
  const int xcd = id & 7, j = id >> 3;            // j 0..63
  const int mg = xcd >> 1, ng = xcd & 1;
  const int m0 = (mg*8 + (j & 7)) * 128;          // 32 m-blocks
  const int n0 = (ng*8 + (j >> 3)) * 64;          // 16 n-blocks

  const f32x4 ZERO4 = {0.f,0.f,0.f,0.f};
  f32x4 acc[4][2];
#pragma unroll
  for (int i=0;i<4;++i)
#pragma unroll
    for (int j2=0;j2<2;++j2) acc[i][j2] = ZERO4;

  const int slot0 = wid*128 + lane, slot1 = slot0 + 64;
  const int sr0 = slot0>>2, sc0 = slot0&3;
  const int sr1 = slot1>>2, sc1 = slot1&3;
  const unsigned short* A0 = A + (size_t)(m0 + sr0)*K + (sc0 ^ ((sr0>>1)&3))*8;
  const unsigned short* A1 = A + (size_t)(m0 + sr1)*K + (sc1 ^ ((sr1>>1)&3))*8;
  const int slotB = wid*64 + lane;
  const int srB = slotB>>2, scB = slotB&3;
  const unsigned short* B0 = Bt + (size_t)(n0 + srB)*K + (scB ^ ((srB>>1)&3))*8;

  G64_STAGE(0, 0);
  G64_STAGE(1, 32);

  for (int ti=0; ti<NT; ++ti){
    const int cur = ti % 3;
    if (ti+2 < NT){
      G64_STAGE((ti+2)%3, (ti+2)*32);
      asm volatile("s_waitcnt vmcnt(6)" ::: "memory");
    } else if (ti+1 < NT){
      asm volatile("s_waitcnt vmcnt(3)" ::: "memory");
    } else {
      asm volatile("s_waitcnt vmcnt(0)" ::: "memory");
    }
    __builtin_amdgcn_s_barrier();
    __builtin_amdgcn_sched_barrier(0);
    G64_COMPUTE(cur);
    __builtin_amdgcn_sched_barrier(0);
    __builtin_amdgcn_s_barrier();
  }

  const int r4 = g*4;
#pragma unroll
  for (int mi=0;mi<4;++mi){
#pragma unroll
    for (int ni=0;ni<2;++ni){
      int col = n0 + wc*32 + ni*16 + rl;
      float bb = bias[col];
#pragma unroll
      for (int e=0;e<4;++e){
        int row = m0 + wr*64 + mi*16 + r4 + e;
        C[(size_t)row*N + col] = acc[mi][ni][e] + bb;
      }
    }
  }
}

// =============================================================
// Sparse flash attention v6 (proven best, sel-based, VGPR 64):
// FIXED-MAX softmax — p = exp2(S - 8). Q prescaled (log2 domain) in
// the QKV GEMM epilogue. Lane-local P rows; cvtpk + ds_bpermute
// redistribution; O^T = V^T*P^T; double-buffered K/V reg prefetch;
// PAIRED balanced blocks + XCD pinning; setprio on MFMA.
// =============================================================
__global__ __launch_bounds__(256) void attn_kernel(const unsigned short* __restrict__ qkv,
                                                   const int* __restrict__ sel,
                                                   unsigned short* __restrict__ ctx){
  const int id = blockIdx.x;                 // 0..767
  const int xcd = id & 7, jj = id >> 3;      // jj 0..95
  const int bh = xcd + 8*(jj/24);
  const int tau = jj % 24;
  const int h = bh & 15, b = bh >> 4;
  int qbl[2]; int nq;
  if (tau < 8){ qbl[0]=tau; qbl[1]=15-tau; nq=2; }
  else        { qbl[0]=tau+8; qbl[1]=0;    nq=1; }

  const int t = threadIdx.x, wid = t >> 6, lane = t & 63;
  const int rl = lane & 15, g = lane >> 4;
  const int q_local = wid*16 + rl;

  __shared__ unsigned short K_s[2][4096];    // [j 64][128B], chunk^(j&7) swizzle
  __shared__ unsigned short V_s[2][4096];    // V^T [d 64][128B], chunk^((d&7)^(d>>3))

  const int jst = t >> 2, cq = t & 3;        // K: row jst, chunks 2cq, 2cq+1
  const int r2 = t >> 3, dq = t & 7;         // V: rows 2r2,2r2+1, d-base dq*8
  const unsigned short* kbase = qkv + (size_t)(b*Sdim + jst)*3072 + 1024 + h*DH + cq*16;
  const unsigned short* vbase = qkv + (size_t)(b*Sdim + 2*r2)*3072 + 2048 + h*DH + dq*8;
  const int kwb0 = jst*128 + (((cq*2  ) ^ (jst&7))<<4);
  const int kwb1 = jst*128 + (((cq*2+1) ^ (jst&7))<<4);
  const f32x4 ZERO4 = {0.f,0.f,0.f,0.f};

  const int src0 = (rl + 16*((2*g  ) & 3)) << 2;
  const int src1 = (rl + 16*((2*g+1) & 3)) << 2;
  const bool hsel = (g >> 1);

  for (int iq=0; iq<nq; ++iq){
    const int qb = qbl[iq];
    const int* selrow = sel + (size_t)(((b*Hdim)+h)*NB + qb) * SEL_STRIDE;
    const int ns = selrow[0];

    const int qg0 = b*Sdim + qb*64 + q_local;
    const unsigned short* qbase = qkv + (size_t)qg0*3072 + h*DH;
    s16x8 qa[2];                 // raw loads — prescale done in GEMM epilogue
    qa[0] = *(const s16x8*)(qbase + g*8);
    qa[1] = *(const s16x8*)(qbase + 32 + g*8);

    f32x4 o[4];                  // O^T: o[f][e] = O[q=q_local][d = f*16 + g*4 + e]
    float l_p = 0.f;             // per-lane partial denominator
#pragma unroll
    for (int f=0; f<4; ++f) o[f] = ZERO4;

    __syncthreads();            // bufs free of prev-qb readers

    int kb = selrow[1];
    s16x8 kr0, kr1, vr0, vr1;
    {
      const size_t off = (size_t)kb*64*3072;
      kr0 = *(const s16x8*)(kbase + off);
      kr1 = *(const s16x8*)(kbase + off + 8);
      vr0 = *(const s16x8*)(vbase + off);
      vr1 = *(const s16x8*)(vbase + off + 3072);
    }

    for (int it=0; it<ns; ++it){
      const int buf = it & 1;
      unsigned short* Kw = &K_s[buf][0];
      unsigned short* Vw = &V_s[buf][0];
      *(s16x8*)((char*)Kw + kwb0) = kr0;
      *(s16x8*)((char*)Kw + kwb1) = kr1;
#pragma unroll
      for (int e=0;e<8;++e){
        const int d1 = dq*8 + e;
        const int sw = (d1&7) ^ (d1>>3);
        const unsigned int pr = (unsigned int)(unsigned short)vr0[e]
                              | ((unsigned int)(unsigned short)vr1[e] << 16);
        *(unsigned int*)((char*)Vw + d1*128 + ((4*r2) ^ (sw<<4))) = pr;
      }
      const int kbcur = kb;
      if (it+1 < ns){
        kb = selrow[2+it];
        const size_t off = (size_t)kb*64*3072;
        kr0 = *(const s16x8*)(kbase + off);
        kr1 = *(const s16x8*)(kbase + off + 8);
        vr0 = *(const s16x8*)(vbase + off);
        vr1 = *(const s16x8*)(vbase + off + 3072);
      }
      __syncthreads();

      // ---- S^T = K Q'^T  (log2 domain via Q prescale) ----
      f32x4 sfT[4];
#pragma unroll
      for (int f=0;f<4;++f) sfT[f] = ZERO4;
      __builtin_amdgcn_s_setprio(1);
#pragma unroll
      for (int kk=0;kk<2;++kk){
#pragma unroll
        for (int f=0;f<4;++f){
          const int jr = f*16 + rl;
          s16x8 kf = *(const s16x8*)((char*)Kw + jr*128 + (((kk*4+g) ^ (jr&7))<<4));
          sfT[f] = __builtin_amdgcn_mfma_f32_16x16x32_bf16(kf, qa[kk], sfT[f], 0,0,0);
        }
      }
      __builtin_amdgcn_s_setprio(0);
      if (kbcur == qb){
#pragma unroll
        for (int f=0;f<4;++f)
#pragma unroll
          for (int e=0;e<4;++e){
            const int j2 = f*16 + g*4 + e;
            if (j2 > q_local) sfT[f][e] = -1e9f;
          }
      }
      // ---- fixed-max softmax weights: p = 2^(S - MFIX) ----
      {
        float rs = 0.f;
#pragma unroll
        for (int f=0;f<4;++f)
#pragma unroll
          for (int e=0;e<4;++e){
            const float p = exp2fast(sfT[f][e] - MFIX);
            sfT[f][e] = p; rs += p;
          }
        l_p += rs;
      }

      unsigned int plo[4], phi[4];
#pragma unroll
      for (int f=0;f<4;++f){
        plo[f] = cvtpk(sfT[f][0], sfT[f][1]);
        phi[f] = cvtpk(sfT[f][2], sfT[f][3]);
      }

#pragma unroll
      for (int kk=0;kk<2;++kk){
        const int f0 = 2*kk, f1 = 2*kk+1;
        unsigned int a0, b0, w0, w1, w2, w3;
        a0 = __builtin_amdgcn_ds_bpermute(src0, plo[f0]);
        b0 = __builtin_amdgcn_ds_bpermute(src0, plo[f1]);
        w0 = hsel ? b0 : a0;
        a0 = __builtin_amdgcn_ds_bpermute(src0, phi[f0]);
        b0 = __builtin_amdgcn_ds_bpermute(src0, phi[f1]);
        w1 = hsel ? b0 : a0;
        a0 = __builtin_amdgcn_ds_bpermute(src1, plo[f0]);
        b0 = __builtin_amdgcn_ds_bpermute(src1, plo[f1]);
        w2 = hsel ? b0 : a0;
        a0 = __builtin_amdgcn_ds_bpermute(src1, phi[f0]);
        b0 = __builtin_amdgcn_ds_bpermute(src1, phi[f1]);
        w3 = hsel ? b0 : a0;
        union { unsigned int u[4]; s16x8 v; } pfc;
        pfc.u[0] = w0; pfc.u[1] = w1; pfc.u[2] = w2; pfc.u[3] = w3;
        const s16x8 pf = pfc.v;
        __builtin_amdgcn_s_setprio(1);
#pragma unroll
        for (int f=0;f<4;++f){
          const int d = f*16 + rl;
          const int sw = (d&7) ^ (d>>3);
          s16x8 vf = *(const s16x8*)((char*)Vw + d*128 + ((64*kk + 16*g) ^ (sw<<4)));
          o[f] = __builtin_amdgcn_mfma_f32_16x16x32_bf16(vf, pf, o[f], 0,0,0);
        }
        __builtin_amdgcn_s_setprio(0);
      }
    }

    {
      float l_r = l_p;
      l_r += __shfl_xor(l_r, 16);
      l_r += __shfl_xor(l_r, 32);
      const float inv = 1.f / l_r;
      unsigned short* crow = ctx + (size_t)qg0*Ddim + h*DH;
#pragma unroll
      for (int f=0;f<4;++f){
        uint2 st;
        st.x = (unsigned int)f2bf(o[f][0]*inv) | ((unsigned int)f2bf(o[f][1]*inv)<<16);
        st.y = (unsigned int)f2bf(o[f][2]*inv) | ((unsigned int)f2bf(o[f][3]*inv)<<16);
        *(uint2*)(crow + f*16 + g*4) = st;
      }
    }
  }
}

// =============================================================
extern "C" void kernel_launch(void* const* d_in, const int* in_sizes, int n_in,
                              void* d_out, int out_size, void* d_ws, size_t ws_size,
                              hipStream_t stream){
  (void)in_sizes; (void)n_in; (void)out_size; (void)ws_size;
  const float* inp  = (const float*)d_in[0];
  const float* ln_g = (const float*)d_in[1];
  const float* ln_b = (const float*)d_in[2];
  const float* Wq   = (const float*)d_in[3];
  const float* bq   = (const float*)d_in[4];
  const float* Wk   = (const float*)d_in[5];
  const float* bk   = (const float*)d_in[6];
  const float* Wv   = (const float*)d_in[7];
  const float* bv   = (const float*)d_in[8];
  const float* Wo   = (const float*)d_in[9];
  const float* bo   = (const float*)d_in[10];

  char* ws = (char*)d_ws;
  unsigned short* xb    = (unsigned short*)(ws + OFF_XB);
  unsigned short* wtqkv = (unsigned short*)(ws + OFF_WTQKV);
  unsigned short* wot   = (unsigned short*)(ws + OFF_WOT);
  unsigned short* qkvb  = (unsigned short*)(ws + OFF_QKV);
  unsigned short* ctx   = (unsigned short*)(ws + OFF_CTX);
  float* xm   = (float*)(ws + OFF_XM);
  float* qm   = (float*)(ws + OFF_QM);
  float* km   = (float*)(ws + OFF_KM);
  float* bqkv = (float*)(ws + OFF_BIASQ);
  int*   sel  = (int*)(ws + OFF_SEL);
  float* part = (float*)(ws + OFF_PART);

  prep_kernel<<<8256, 256, 0, stream>>>(inp, ln_g, ln_b, Wq, Wk, Wv, Wo,
                                        bq, bk, bv, xb, xm, wtqkv, wot, bqkv);
  qmkm_part<<<dim3(4,32,2), 256, 0, stream>>>(xm, Wq, Wk, part);
  qmkm_reduce<<<dim3(256,2), 256, 0, stream>>>(part, bq, bk, qm, km);
  gemm_qkv_topk<<<1792, 256, 0, stream>>>(xb, wtqkv, bqkv, qkvb, qm, km, sel);
  attn_kernel<<<768, 256, 0, stream>>>(qkvb, sel, ctx);
  gemm_bt64<<<dim3(16,32), 256, 0, stream>>>(ctx, wot, bo, (float*)d_out, 1024);
}